// Round 1
// baseline (2522.473 us; speedup 1.0000x reference)
//
#include <hip/hip_runtime.h>

#define NT    16384
#define DDIM  512
#define HDIM  1365
#define HPAD  1408
#define NEXP  16
#define HC    64
#define NCHUNK (HPAD / HC)   // 22
#define MT    64

typedef unsigned short u16;
typedef unsigned int   u32;
typedef __attribute__((ext_vector_type(8))) __bf16 bf16x8;
typedef __attribute__((ext_vector_type(4))) float  f32x4;

__device__ __forceinline__ u16 f2bf(float f) {
  union { float f; u32 u; } v; v.f = f;
  u32 u = v.u;
  u += 0x7fffu + ((u >> 16) & 1u);   // round-to-nearest-even
  return (u16)(u >> 16);
}

__device__ __forceinline__ f32x4 mfma16(bf16x8 a, bf16x8 b, f32x4 c) {
  return __builtin_amdgcn_mfma_f32_16x16x32_bf16(a, b, c, 0, 0, 0);
}

// ---------------- x fp32 -> bf16 ----------------
__global__ void convert_x_kernel(const float* __restrict__ in, u16* __restrict__ out, int n8) {
  int i = blockIdx.x * 256 + threadIdx.x;
  if (i >= n8) return;
  float4 a = ((const float4*)in)[2 * i];
  float4 b = ((const float4*)in)[2 * i + 1];
  u16 r[8] = {f2bf(a.x), f2bf(a.y), f2bf(a.z), f2bf(a.w),
              f2bf(b.x), f2bf(b.y), f2bf(b.z), f2bf(b.w)};
  ((uint4*)out)[i] = *(const uint4*)r;
}

// ---------- w1/w2 (E,D,H) fp32 -> (E,HPAD,D) bf16, zero-padded ----------
__global__ void transpose12_kernel(const float* __restrict__ in, u16* __restrict__ out) {
  __shared__ float tile[32][33];
  int e = blockIdx.z;
  int h0 = blockIdx.x * 32, d0 = blockIdx.y * 32;
  int tx = threadIdx.x, ty = threadIdx.y;
#pragma unroll
  for (int r = 0; r < 4; ++r) {
    int d = d0 + ty + r * 8, h = h0 + tx;
    float v = (h < HDIM) ? in[((size_t)e * DDIM + d) * HDIM + h] : 0.f;
    tile[ty + r * 8][tx] = v;
  }
  __syncthreads();
#pragma unroll
  for (int r = 0; r < 4; ++r) {
    int h = h0 + ty + r * 8, d = d0 + tx;
    out[((size_t)e * HPAD + h) * DDIM + d] = f2bf(tile[tx][ty + r * 8]);
  }
}

// ---------- w3 (E,H,D) fp32 -> (E,D,HPAD) bf16, zero-padded ----------
__global__ void transpose3_kernel(const float* __restrict__ in, u16* __restrict__ out) {
  __shared__ float tile[32][33];
  int e = blockIdx.z;
  int d0 = blockIdx.x * 32, h0 = blockIdx.y * 32;
  int tx = threadIdx.x, ty = threadIdx.y;
#pragma unroll
  for (int r = 0; r < 4; ++r) {
    int h = h0 + ty + r * 8, d = d0 + tx;
    float v = (h < HDIM) ? in[((size_t)e * HDIM + h) * DDIM + d] : 0.f;
    tile[ty + r * 8][tx] = v;
  }
  __syncthreads();
#pragma unroll
  for (int r = 0; r < 4; ++r) {
    int d = d0 + ty + r * 8, h = h0 + tx;
    out[((size_t)e * DDIM + d) * HPAD + h] = f2bf(tile[tx][ty + r * 8]);
  }
}

// ---------------- routing: logits, top-4, softmax, append ----------------
__global__ void routing_kernel(const float* __restrict__ x, const float* __restrict__ gw,
                               const float* __restrict__ rbias,
                               int* __restrict__ counts, int* __restrict__ tok_list,
                               float* __restrict__ w_list) {
  int t = blockIdx.x;
  int lane = threadIdx.x;
  float acc[NEXP];
#pragma unroll
  for (int e = 0; e < NEXP; ++e) acc[e] = 0.f;
  const float* xr = x + (size_t)t * DDIM;
  for (int d = lane; d < DDIM; d += 64) {
    float xv = xr[d];
    const float4* g4 = (const float4*)(gw + d * NEXP);
    float4 g0 = g4[0], g1 = g4[1], g2 = g4[2], g3 = g4[3];
    acc[0] += xv * g0.x; acc[1] += xv * g0.y; acc[2]  += xv * g0.z; acc[3]  += xv * g0.w;
    acc[4] += xv * g1.x; acc[5] += xv * g1.y; acc[6]  += xv * g1.z; acc[7]  += xv * g1.w;
    acc[8] += xv * g2.x; acc[9] += xv * g2.y; acc[10] += xv * g2.z; acc[11] += xv * g2.w;
    acc[12] += xv * g3.x; acc[13] += xv * g3.y; acc[14] += xv * g3.z; acc[15] += xv * g3.w;
  }
#pragma unroll
  for (int e = 0; e < NEXP; ++e) {
    float v = acc[e];
#pragma unroll
    for (int off = 32; off; off >>= 1) v += __shfl_xor(v, off);
    acc[e] = v + rbias[e];
  }
  if (lane == 0) {
    int sel[4]; float sv[4];
    unsigned used = 0;
#pragma unroll
    for (int i = 0; i < 4; ++i) {
      float best = -1e30f; int bi = 0;
#pragma unroll
      for (int e = 0; e < NEXP; ++e) {
        bool ok = !((used >> e) & 1u) && acc[e] > best;
        best = ok ? acc[e] : best;
        bi   = ok ? e : bi;
      }
      used |= 1u << bi; sel[i] = bi; sv[i] = best;
    }
    float m = sv[0];
    float ex[4]; float s = 0.f;
#pragma unroll
    for (int i = 0; i < 4; ++i) { ex[i] = __expf(sv[i] - m); s += ex[i]; }
    float inv = 1.f / s;
#pragma unroll
    for (int i = 0; i < 4; ++i) {
      int e = sel[i];
      int pos = atomicAdd(&counts[e], 1);
      tok_list[e * NT + pos] = t;
      w_list[e * NT + pos]  = ex[i] * inv;
    }
  }
}

// ---------------- fused grouped expert: GEMM1 + SwiGLU + GEMM2 ----------------
// 512 threads = 8 waves as 2(m) x 4(n). Tile: 64 tokens x full D=512 out.
template <bool SHARED>
__global__ __launch_bounds__(512, 4) void moe_expert_kernel(
    const u16* __restrict__ x_bf,
    const u16* __restrict__ Wa, const u16* __restrict__ Wb, const u16* __restrict__ Wc,
    const int* __restrict__ counts, const int* __restrict__ tok_list,
    const float* __restrict__ w_list, float* __restrict__ out) {
  __shared__ u16  x_tile[MT * DDIM];   // 64 KiB, XOR-swizzled
  __shared__ u16  h_tile[MT * HC];     // 8 KiB, XOR-swizzled
  __shared__ int  s_tok[MT];
  __shared__ float s_w[MT];

  int e = blockIdx.y;
  int m0 = blockIdx.x * MT;
  const u16 *W1, *W2, *W3;
  int cnt;
  if constexpr (SHARED) {
    W1 = Wa; W2 = Wb; W3 = Wc; cnt = NT;
  } else {
    cnt = counts[e];
    if (m0 >= cnt) return;
    W1 = Wa + (size_t)e * HPAD * DDIM;
    W2 = Wb + (size_t)e * HPAD * DDIM;
    W3 = Wc + (size_t)e * DDIM * HPAD;
  }
  int rem = cnt - m0; if (rem > MT) rem = MT;

  int tid = threadIdx.x;
  if (tid < MT) {
    int tk; float wv;
    if constexpr (SHARED) {
      tk = m0 + tid; wv = 1.0f;
    } else {
      int idx = (tid < rem) ? (m0 + tid) : m0;
      tk = tok_list[e * NT + idx];
      wv = (tid < rem) ? w_list[e * NT + idx] : 0.f;
    }
    s_tok[tid] = tk; s_w[tid] = wv;
  }
  __syncthreads();

  // stage x rows, 16B chunks, swizzle byte^((row&7)<<4) (==u16 idx ^ (row&7)<<3)
#pragma unroll
  for (int i = 0; i < 8; ++i) {
    int c = tid + i * 512;            // 0..4095
    int row = c >> 6, cc = c & 63;
    uint4 v = *(const uint4*)(x_bf + ((size_t)s_tok[row] << 9) + (cc << 3));
    int idx = (row << 9) + (cc << 3);
    *(uint4*)&x_tile[idx ^ ((row & 7) << 3)] = v;
  }
  __syncthreads();

  int wid = tid >> 6, lane = tid & 63;
  int wm = wid >> 2, wn = wid & 3;    // wave grid 2x4
  int lr = lane & 15, lk = lane >> 4; // frag coords

  f32x4 acc[2][8] = {};

  for (int ch = 0; ch < NCHUNK; ++ch) {
    int hcb = ch * HC;
    // ---- GEMM1: g,u [64 x 64]; this wave: rows wm*32+, cols wn*16+
    f32x4 ga[2] = {}, ua[2] = {};
    {
      const u16* w1r = W1 + (size_t)(hcb + wn * 16 + lr) * DDIM;
      const u16* w2r = W2 + (size_t)(hcb + wn * 16 + lr) * DDIM;
#pragma unroll 4
      for (int ks = 0; ks < 16; ++ks) {
        int k0 = ks * 32 + lk * 8;
        bf16x8 b1 = *(const bf16x8*)(w1r + k0);
        bf16x8 b2 = *(const bf16x8*)(w2r + k0);
#pragma unroll
        for (int mf = 0; mf < 2; ++mf) {
          int m = wm * 32 + mf * 16 + lr;
          int idx = (m << 9) + k0;
          bf16x8 a = *(const bf16x8*)&x_tile[idx ^ ((m & 7) << 3)];
          ga[mf] = mfma16(a, b1, ga[mf]);
          ua[mf] = mfma16(a, b2, ua[mf]);
        }
      }
    }
    __syncthreads();  // prev-chunk GEMM2 h_tile reads complete
#pragma unroll
    for (int mf = 0; mf < 2; ++mf) {
#pragma unroll
      for (int j = 0; j < 4; ++j) {
        float g = ga[mf][j], u = ua[mf][j];
        float hv = g * u / (1.f + __expf(-g));   // swish(g)*u
        int m = wm * 32 + mf * 16 + lk * 4 + j;
        int idx = (m << 6) + wn * 16 + lr;
        h_tile[idx ^ ((m & 7) << 3)] = f2bf(hv);
      }
    }
    __syncthreads();
    // ---- GEMM2: out[rows wm*32+32][cols wn*128+128] += h @ w3_chunk
#pragma unroll
    for (int ks = 0; ks < 2; ++ks) {
      int k0 = ks * 32 + lk * 8;
      bf16x8 a[2];
#pragma unroll
      for (int mf = 0; mf < 2; ++mf) {
        int m = wm * 32 + mf * 16 + lr;
        int idx = (m << 6) + k0;
        a[mf] = *(const bf16x8*)&h_tile[idx ^ ((m & 7) << 3)];
      }
#pragma unroll
      for (int nf = 0; nf < 8; ++nf) {
        int n = wn * 128 + nf * 16 + lr;
        bf16x8 b = *(const bf16x8*)(W3 + (size_t)n * HPAD + hcb + k0);
        acc[0][nf] = mfma16(a[0], b, acc[0][nf]);
        acc[1][nf] = mfma16(a[1], b, acc[1][nf]);
      }
    }
  }

  // ---- epilogue: weight & write/accumulate
#pragma unroll
  for (int mf = 0; mf < 2; ++mf) {
#pragma unroll
    for (int j = 0; j < 4; ++j) {
      int ml = wm * 32 + mf * 16 + lk * 4 + j;
      if (ml < rem) {
        float wv = s_w[ml];
        float* orow = out + ((size_t)s_tok[ml] << 9) + wn * 128 + lr;
#pragma unroll
        for (int nf = 0; nf < 8; ++nf) {
          float v = acc[mf][nf][j] * wv;
          if constexpr (SHARED) orow[nf * 16] = v;
          else atomicAdd(&orow[nf * 16], v);
        }
      }
    }
  }
}

extern "C" void kernel_launch(void* const* d_in, const int* in_sizes, int n_in,
                              void* d_out, int out_size, void* d_ws, size_t ws_size,
                              hipStream_t stream) {
  const float* x      = (const float*)d_in[0];
  const float* gate_w = (const float*)d_in[1];
  const float* rbias  = (const float*)d_in[2];
  const float* w1     = (const float*)d_in[3];
  const float* w2     = (const float*)d_in[4];
  const float* w3     = (const float*)d_in[5];
  const float* sw1    = (const float*)d_in[6];
  const float* sw2    = (const float*)d_in[7];
  const float* sw3    = (const float*)d_in[8];
  float* out = (float*)d_out;

  char* ws = (char*)d_ws;
  size_t off = 0;
  auto alloc = [&](size_t bytes) -> char* {
    char* p = ws + off;
    off += (bytes + 255) & ~(size_t)255;
    return p;
  };
  u16* x_bf  = (u16*)alloc((size_t)NT * DDIM * 2);
  u16* w1t   = (u16*)alloc((size_t)NEXP * HPAD * DDIM * 2);
  u16* w2t   = (u16*)alloc((size_t)NEXP * HPAD * DDIM * 2);
  u16* w3t   = (u16*)alloc((size_t)NEXP * DDIM * HPAD * 2);
  u16* sw1t  = (u16*)alloc((size_t)HPAD * DDIM * 2);
  u16* sw2t  = (u16*)alloc((size_t)HPAD * DDIM * 2);
  u16* sw3t  = (u16*)alloc((size_t)DDIM * HPAD * 2);
  int* counts    = (int*)alloc(256);
  int* tok_list  = (int*)alloc((size_t)NEXP * NT * 4);
  float* w_list  = (float*)alloc((size_t)NEXP * NT * 4);
  (void)in_sizes; (void)n_in; (void)out_size; (void)ws_size;

  hipMemsetAsync(counts, 0, 256, stream);

  int n8 = NT * DDIM / 8;
  convert_x_kernel<<<n8 / 256, 256, 0, stream>>>(x, x_bf, n8);

  dim3 tb(32, 8);
  transpose12_kernel<<<dim3(HPAD / 32, DDIM / 32, NEXP), tb, 0, stream>>>(w1, w1t);
  transpose12_kernel<<<dim3(HPAD / 32, DDIM / 32, NEXP), tb, 0, stream>>>(w2, w2t);
  transpose12_kernel<<<dim3(HPAD / 32, DDIM / 32, 1),    tb, 0, stream>>>(sw1, sw1t);
  transpose12_kernel<<<dim3(HPAD / 32, DDIM / 32, 1),    tb, 0, stream>>>(sw2, sw2t);
  transpose3_kernel<<<dim3(DDIM / 32, HPAD / 32, NEXP),  tb, 0, stream>>>(w3, w3t);
  transpose3_kernel<<<dim3(DDIM / 32, HPAD / 32, 1),     tb, 0, stream>>>(sw3, sw3t);

  routing_kernel<<<NT, 64, 0, stream>>>(x, gate_w, rbias, counts, tok_list, w_list);

  // shared expert first: plain stores initialize every output element
  moe_expert_kernel<true><<<dim3(NT / MT, 1), 512, 0, stream>>>(
      x_bf, sw1t, sw2t, sw3t, counts, tok_list, w_list, out);
  // routed experts accumulate on top
  moe_expert_kernel<false><<<dim3(NT / MT, NEXP), 512, 0, stream>>>(
      x_bf, w1t, w2t, w3t, counts, tok_list, w_list, out);
}

// Round 3
// 2275.275 us; speedup vs baseline: 1.1086x; 1.1086x over previous
//
#include <hip/hip_runtime.h>

#define NT    16384
#define DDIM  512
#define HDIM  1365
#define HPAD  1408
#define NEXP  16
#define BK    64
#define MAXTILES 656
#define MAXSLOTS 84096   // 657 * 128

typedef unsigned short u16;
typedef unsigned int   u32;
typedef __attribute__((ext_vector_type(8))) __bf16 bf16x8;
typedef __attribute__((ext_vector_type(4))) float  f32x4;
typedef __attribute__((address_space(3))) void lds_void;
typedef __attribute__((address_space(1))) void glb_void;

__device__ __forceinline__ u16 f2bf(float f) {
  union { float f; u32 u; } v; v.f = f;
  u32 u = v.u;
  u += 0x7fffu + ((u >> 16) & 1u);
  return (u16)(u >> 16);
}

__device__ __forceinline__ float bf2f(u16 b) {
  union { u32 u; float f; } v; v.u = ((u32)b) << 16;
  return v.f;
}

__device__ __forceinline__ f32x4 mfma16(bf16x8 a, bf16x8 b, f32x4 c) {
  return __builtin_amdgcn_mfma_f32_16x16x32_bf16(a, b, c, 0, 0, 0);
}

__device__ __forceinline__ void gload16(const u16* g, u16* l) {
  __builtin_amdgcn_global_load_lds((const glb_void*)g, (lds_void*)l, 16, 0, 0);
}

// swizzled LDS fragment read: tile is [rows][64] u16, row stride 128B
__device__ __forceinline__ bf16x8 lds_frag(const u16* base, int row, int e0) {
  int b = ((row << 7) + (e0 << 1)) ^ ((row & 7) << 4);
  return *(const bf16x8*)((const char*)base + b);
}

// XCD-aware bijective tile swizzle (MAXTILES = 656 = 8*82)
__device__ __forceinline__ int tile_swz(int bid) {
  return (bid & 7) * (MAXTILES / 8) + (bid >> 3);
}

// ---------------- x fp32 -> bf16 ----------------
__global__ void convert_x_kernel(const float* __restrict__ in, u16* __restrict__ out, int n8) {
  int i = blockIdx.x * 256 + threadIdx.x;
  if (i >= n8) return;
  float4 a = ((const float4*)in)[2 * i];
  float4 b = ((const float4*)in)[2 * i + 1];
  u16 r[8] = {f2bf(a.x), f2bf(a.y), f2bf(a.z), f2bf(a.w),
              f2bf(b.x), f2bf(b.y), f2bf(b.z), f2bf(b.w)};
  ((uint4*)out)[i] = *(const uint4*)r;
}

// ---------- w1/w2 (E,D,H) fp32 -> (E,HPAD,D) bf16, zero-padded ----------
__global__ void transpose12_kernel(const float* __restrict__ in, u16* __restrict__ out) {
  __shared__ float tile[32][33];
  int e = blockIdx.z;
  int h0 = blockIdx.x * 32, d0 = blockIdx.y * 32;
  int tx = threadIdx.x, ty = threadIdx.y;
#pragma unroll
  for (int r = 0; r < 4; ++r) {
    int d = d0 + ty + r * 8, h = h0 + tx;
    float v = (h < HDIM) ? in[((size_t)e * DDIM + d) * HDIM + h] : 0.f;
    tile[ty + r * 8][tx] = v;
  }
  __syncthreads();
#pragma unroll
  for (int r = 0; r < 4; ++r) {
    int h = h0 + ty + r * 8, d = d0 + tx;
    out[((size_t)e * HPAD + h) * DDIM + d] = f2bf(tile[tx][ty + r * 8]);
  }
}

// ---------- w3 (E,H,D) fp32 -> (E,D,HPAD) bf16, zero-padded ----------
__global__ void transpose3_kernel(const float* __restrict__ in, u16* __restrict__ out) {
  __shared__ float tile[32][33];
  int e = blockIdx.z;
  int d0 = blockIdx.x * 32, h0 = blockIdx.y * 32;
  int tx = threadIdx.x, ty = threadIdx.y;
#pragma unroll
  for (int r = 0; r < 4; ++r) {
    int h = h0 + ty + r * 8, d = d0 + tx;
    float v = (h < HDIM) ? in[((size_t)e * HDIM + h) * DDIM + d] : 0.f;
    tile[ty + r * 8][tx] = v;
  }
  __syncthreads();
#pragma unroll
  for (int r = 0; r < 4; ++r) {
    int d = d0 + ty + r * 8, h = h0 + tx;
    out[((size_t)e * DDIM + d) * HPAD + h] = f2bf(tile[tx][ty + r * 8]);
  }
}

// ---------------- routing: logits, top-4, softmax ----------------
__global__ void routing_kernel(const float* __restrict__ x, const float* __restrict__ gw,
                               const float* __restrict__ rbias,
                               int* __restrict__ counts, int* __restrict__ top_e,
                               float* __restrict__ top_w, int* __restrict__ top_pos) {
  int t = blockIdx.x;
  int lane = threadIdx.x;
  float acc[NEXP];
#pragma unroll
  for (int e = 0; e < NEXP; ++e) acc[e] = 0.f;
  const float* xr = x + (size_t)t * DDIM;
  for (int d = lane; d < DDIM; d += 64) {
    float xv = xr[d];
    const float4* g4 = (const float4*)(gw + d * NEXP);
    float4 g0 = g4[0], g1 = g4[1], g2 = g4[2], g3 = g4[3];
    acc[0] += xv * g0.x; acc[1] += xv * g0.y; acc[2]  += xv * g0.z; acc[3]  += xv * g0.w;
    acc[4] += xv * g1.x; acc[5] += xv * g1.y; acc[6]  += xv * g1.z; acc[7]  += xv * g1.w;
    acc[8] += xv * g2.x; acc[9] += xv * g2.y; acc[10] += xv * g2.z; acc[11] += xv * g2.w;
    acc[12] += xv * g3.x; acc[13] += xv * g3.y; acc[14] += xv * g3.z; acc[15] += xv * g3.w;
  }
#pragma unroll
  for (int e = 0; e < NEXP; ++e) {
    float v = acc[e];
#pragma unroll
    for (int off = 32; off; off >>= 1) v += __shfl_xor(v, off);
    acc[e] = v + rbias[e];
  }
  if (lane == 0) {
    int sel[4]; float sv[4];
    unsigned used = 0;
#pragma unroll
    for (int i = 0; i < 4; ++i) {
      float best = -1e30f; int bi = 0;
#pragma unroll
      for (int e = 0; e < NEXP; ++e) {
        bool ok = !((used >> e) & 1u) && acc[e] > best;
        best = ok ? acc[e] : best;
        bi   = ok ? e : bi;
      }
      used |= 1u << bi; sel[i] = bi; sv[i] = best;
    }
    float m = sv[0];
    float ex[4]; float s = 0.f;
#pragma unroll
    for (int i = 0; i < 4; ++i) { ex[i] = __expf(sv[i] - m); s += ex[i]; }
    float inv = 1.f / s;
#pragma unroll
    for (int i = 0; i < 4; ++i) {
      int e = sel[i];
      int pos = atomicAdd(&counts[e], 1);
      top_e[t * 4 + i] = e;
      top_pos[t * 4 + i] = pos;
      top_w[t * 4 + i] = ex[i] * inv;
    }
  }
}

// ---------------- finalize: padded slot offsets + tile descriptors ----------------
__global__ void finalize_kernel(const int* __restrict__ counts, int* __restrict__ slot_off,
                                int* __restrict__ ntiles, int2* __restrict__ desc) {
  if (threadIdx.x != 0) return;
  int off = 0, td = 0;
  for (int e = 0; e < 17; ++e) {
    int c = (e == 16) ? NT : counts[e];
    slot_off[e] = off;
    int nt = (c + 127) / 128;
    for (int i = 0; i < nt; ++i) { desc[td] = make_int2(e, off + i * 128); ++td; }
    off += nt * 128;
  }
  slot_off[17] = off;
  *ntiles = td;
}

// ---------------- scatter: per-slot token / weight, per-token slot list ----------------
__global__ void scatter_kernel(const int* __restrict__ top_e, const float* __restrict__ top_w,
                               const int* __restrict__ top_pos, const int* __restrict__ slot_off,
                               int* __restrict__ tok_pad, float* __restrict__ w_pad,
                               int* __restrict__ pos_list) {
  int t = blockIdx.x * 256 + threadIdx.x;
  if (t >= NT) return;
#pragma unroll
  for (int i = 0; i < 4; ++i) {
    int e = top_e[t * 4 + i];
    int slot = slot_off[e] + top_pos[t * 4 + i];
    tok_pad[slot] = t;
    w_pad[slot] = top_w[t * 4 + i];
    pos_list[t * 4 + i] = slot;
  }
  int sh = slot_off[16] + t;
  tok_pad[sh] = t;
  w_pad[sh] = 1.f;
}

// ---------------- K1: grouped GEMM1 + SwiGLU -> h bf16 (slot chunk [lo,hi)) ----------
// tile: 128 slots x 64 h-cols. B-tile rows 0..63 = W1^T rows n0.., 64..127 = W2^T rows n0..
// output cols 0..63 = g, 64..127 = u; SwiGLU paired via LDS round-trip in epilogue.
__global__ __launch_bounds__(512, 2) void gemm1_kernel(
    const u16* __restrict__ x_bf, const u16* __restrict__ w1t, const u16* __restrict__ w2t,
    const u16* __restrict__ sw1t, const u16* __restrict__ sw2t,
    const int* __restrict__ ntiles, const int2* __restrict__ desc,
    const int* __restrict__ tok_pad, u16* __restrict__ h, int lo, int hi) {
  int bx = tile_swz(blockIdx.x);
  if (bx >= *ntiles) return;
  int2 de = desc[bx];
  int e = de.x, m0 = de.y;
  if (m0 < lo || m0 >= hi) return;
  int n0 = blockIdx.y * 64;
  const u16* W1 = (e == 16) ? sw1t : (w1t + (size_t)e * HPAD * DDIM);
  const u16* W2 = (e == 16) ? sw2t : (w2t + (size_t)e * HPAD * DDIM);

  __shared__ u16 smem[32768];           // 64 KiB: xs dbuf 32K | bs dbuf 32K
  u16* xs = smem;
  u16* bs = smem + 16384;

  int tid = threadIdx.x, w = tid >> 6, lane = tid & 63;
  int wm = w >> 2, wn = w & 3, lr = lane & 15, lk = lane >> 4;

  int r0 = (w << 4) + (lane >> 3);                 // tile row 0..127 (8 lanes/row)
  int ce = (((lane & 7) ^ (lane >> 3)) << 3);      // pre-swizzled source elem
  const u16* xg0 = x_bf + (size_t)tok_pad[m0 + r0] * DDIM + ce;
  const u16* xg1 = x_bf + (size_t)tok_pad[m0 + r0 + 8] * DDIM + ce;
  const u16* Bsrc = (w < 4) ? W1 : W2;
  int br0 = n0 + ((w & 3) << 4) + (lane >> 3);
  const u16* bg0 = Bsrc + (size_t)br0 * DDIM + ce;
  const u16* bg1 = bg0 + (size_t)8 * DDIM;

  auto stage = [&](int ks, int buf) {
    int k0 = ks * BK;
    u16* xd = xs + buf * 8192 + (w << 10);
    u16* bd = bs + buf * 8192 + (w << 10);
    gload16(xg0 + k0, xd);
    gload16(xg1 + k0, xd + 512);
    gload16(bg0 + k0, bd);
    gload16(bg1 + k0, bd + 512);
  };

  f32x4 acc[4][2] = {};
  stage(0, 0);
  __syncthreads();

  for (int ks = 0; ks < DDIM / BK; ++ks) {
    int cur = ks & 1;
    if (ks + 1 < DDIM / BK) stage(ks + 1, cur ^ 1);
    const u16* xb = xs + cur * 8192;
    const u16* bb = bs + cur * 8192;
#pragma unroll
    for (int kf = 0; kf < 2; ++kf) {
      int e0 = kf * 32 + lk * 8;
      bf16x8 b0 = lds_frag(bb, wn * 32 + lr, e0);
      bf16x8 b1 = lds_frag(bb, wn * 32 + 16 + lr, e0);
#pragma unroll
      for (int mf = 0; mf < 4; ++mf) {
        bf16x8 a = lds_frag(xb, wm * 64 + mf * 16 + lr, e0);
        acc[mf][0] = mfma16(a, b0, acc[mf][0]);
        acc[mf][1] = mfma16(a, b1, acc[mf][1]);
      }
    }
    __syncthreads();
  }

  // epilogue: park g/u in LDS (reuse staging buffers), pair, SwiGLU, store h
  float* g_lds = (float*)smem;            // [128][64] f32
  float* u_lds = (float*)(smem + 16384);  // [128][64] f32
#pragma unroll
  for (int mf = 0; mf < 4; ++mf)
#pragma unroll
    for (int nf = 0; nf < 2; ++nf)
#pragma unroll
      for (int j = 0; j < 4; ++j) {
        int row = wm * 64 + mf * 16 + lk * 4 + j;
        int col = wn * 32 + nf * 16 + lr;
        if (col < 64) g_lds[(row << 6) + col] = acc[mf][nf][j];
        else          u_lds[(row << 6) + col - 64] = acc[mf][nf][j];
      }
  __syncthreads();
  int col = tid & 63, rg = tid >> 6;
#pragma unroll
  for (int rr = 0; rr < 16; ++rr) {
    int row = (rg << 4) + rr;
    float g = g_lds[(row << 6) + col];
    float u = u_lds[(row << 6) + col];
    float hv = g * u / (1.f + __expf(-g));
    h[(size_t)(m0 - lo + row) * HPAD + n0 + col] = f2bf(hv);
  }
}

// ---------------- K2: grouped GEMM2, weighted (slot chunk [lo,hi)) ----------------
// tile 128 slots x 128 d-cols, K = HPAD. YMODE: write y bf16; else atomicAdd into out.
template <bool YMODE>
__global__ __launch_bounds__(512, 2) void gemm2_kernel(
    const u16* __restrict__ h, const u16* __restrict__ w3t, const u16* __restrict__ sw3t,
    const int* __restrict__ ntiles, const int2* __restrict__ desc,
    const int* __restrict__ tok_pad, const float* __restrict__ w_pad,
    u16* __restrict__ y, float* __restrict__ out, int lo, int hi) {
  int bx = tile_swz(blockIdx.x);
  if (bx >= *ntiles) return;
  int2 de = desc[bx];
  int e = de.x, m0 = de.y;
  if (m0 < lo || m0 >= hi) return;
  int n0 = blockIdx.y * 128;
  const u16* W3 = (e == 16) ? sw3t : (w3t + (size_t)e * DDIM * HPAD);

  __shared__ u16 smem[32768];
  u16* hs = smem;
  u16* ws3 = smem + 16384;

  int tid = threadIdx.x, w = tid >> 6, lane = tid & 63;
  int wm = w >> 2, wn = w & 3, lr = lane & 15, lk = lane >> 4;

  int r0 = (w << 4) + (lane >> 3);
  int ce = (((lane & 7) ^ (lane >> 3)) << 3);
  const u16* hg0 = h + (size_t)(m0 - lo + r0) * HPAD + ce;
  const u16* hg1 = hg0 + (size_t)8 * HPAD;
  const u16* wg0 = W3 + (size_t)(n0 + r0) * HPAD + ce;
  const u16* wg1 = wg0 + (size_t)8 * HPAD;

  auto stage = [&](int ks, int buf) {
    int k0 = ks * BK;
    u16* hd = hs + buf * 8192 + (w << 10);
    u16* wd = ws3 + buf * 8192 + (w << 10);
    gload16(hg0 + k0, hd);
    gload16(hg1 + k0, hd + 512);
    gload16(wg0 + k0, wd);
    gload16(wg1 + k0, wd + 512);
  };

  f32x4 acc[4][2] = {};
  stage(0, 0);
  __syncthreads();

  for (int ks = 0; ks < HPAD / BK; ++ks) {
    int cur = ks & 1;
    if (ks + 1 < HPAD / BK) stage(ks + 1, cur ^ 1);
    const u16* hb = hs + cur * 8192;
    const u16* wb = ws3 + cur * 8192;
#pragma unroll
    for (int kf = 0; kf < 2; ++kf) {
      int e0 = kf * 32 + lk * 8;
      bf16x8 b0 = lds_frag(wb, wn * 32 + lr, e0);
      bf16x8 b1 = lds_frag(wb, wn * 32 + 16 + lr, e0);
#pragma unroll
      for (int mf = 0; mf < 4; ++mf) {
        bf16x8 a = lds_frag(hb, wm * 64 + mf * 16 + lr, e0);
        acc[mf][0] = mfma16(a, b0, acc[mf][0]);
        acc[mf][1] = mfma16(a, b1, acc[mf][1]);
      }
    }
    __syncthreads();
  }

#pragma unroll
  for (int mf = 0; mf < 4; ++mf)
#pragma unroll
    for (int j = 0; j < 4; ++j) {
      int row = wm * 64 + mf * 16 + lk * 4 + j;
      float wv = w_pad[m0 + row];
      if constexpr (YMODE) {
        u16* yrow = y + (size_t)(m0 + row) * DDIM + n0;
#pragma unroll
        for (int nf = 0; nf < 2; ++nf)
          yrow[wn * 32 + nf * 16 + lr] = f2bf(acc[mf][nf][j] * wv);
      } else {
        float* orow = out + (size_t)tok_pad[m0 + row] * DDIM + n0;
#pragma unroll
        for (int nf = 0; nf < 2; ++nf)
          atomicAdd(&orow[wn * 32 + nf * 16 + lr], acc[mf][nf][j] * wv);
      }
    }
}

// ---------------- reduce: out[t] = y_shared + sum of 4 routed y ----------------
__global__ void reduce_kernel(const u16* __restrict__ y, const int* __restrict__ pos_list,
                              const int* __restrict__ slot_off, float* __restrict__ out) {
  int t = blockIdx.x;
  int c = threadIdx.x;   // 128 threads, 4 elems each
  int4 pl = ((const int4*)pos_list)[t];
  int sh = slot_off[16] + t;
  ushort4 a = ((const ushort4*)(y + (size_t)sh * DDIM))[c];
  ushort4 b = ((const ushort4*)(y + (size_t)pl.x * DDIM))[c];
  ushort4 d = ((const ushort4*)(y + (size_t)pl.y * DDIM))[c];
  ushort4 e = ((const ushort4*)(y + (size_t)pl.z * DDIM))[c];
  ushort4 f = ((const ushort4*)(y + (size_t)pl.w * DDIM))[c];
  float4 s;
  s.x = bf2f(a.x) + bf2f(b.x) + bf2f(d.x) + bf2f(e.x) + bf2f(f.x);
  s.y = bf2f(a.y) + bf2f(b.y) + bf2f(d.y) + bf2f(e.y) + bf2f(f.y);
  s.z = bf2f(a.z) + bf2f(b.z) + bf2f(d.z) + bf2f(e.z) + bf2f(f.z);
  s.w = bf2f(a.w) + bf2f(b.w) + bf2f(d.w) + bf2f(e.w) + bf2f(f.w);
  ((float4*)(out + (size_t)t * DDIM))[c] = s;
}

extern "C" void kernel_launch(void* const* d_in, const int* in_sizes, int n_in,
                              void* d_out, int out_size, void* d_ws, size_t ws_size,
                              hipStream_t stream) {
  const float* x      = (const float*)d_in[0];
  const float* gate_w = (const float*)d_in[1];
  const float* rbias  = (const float*)d_in[2];
  const float* w1     = (const float*)d_in[3];
  const float* w2     = (const float*)d_in[4];
  const float* w3     = (const float*)d_in[5];
  const float* sw1    = (const float*)d_in[6];
  const float* sw2    = (const float*)d_in[7];
  const float* sw3    = (const float*)d_in[8];
  float* out = (float*)d_out;

  char* ws = (char*)d_ws;
  size_t off = 0;
  auto alloc = [&](size_t bytes) -> char* {
    char* p = ws + off;
    off += (bytes + 255) & ~(size_t)255;
    return p;
  };
  u16* x_bf  = (u16*)alloc((size_t)NT * DDIM * 2);
  u16* w1t   = (u16*)alloc((size_t)NEXP * HPAD * DDIM * 2);
  u16* w2t   = (u16*)alloc((size_t)NEXP * HPAD * DDIM * 2);
  u16* w3t   = (u16*)alloc((size_t)NEXP * DDIM * HPAD * 2);
  u16* sw1t  = (u16*)alloc((size_t)HPAD * DDIM * 2);
  u16* sw2t  = (u16*)alloc((size_t)HPAD * DDIM * 2);
  u16* sw3t  = (u16*)alloc((size_t)DDIM * HPAD * 2);
  int*   counts   = (int*)alloc(64 * 4);
  int*   top_e    = (int*)alloc((size_t)NT * 4 * 4);
  float* top_w    = (float*)alloc((size_t)NT * 4 * 4);
  int*   top_pos  = (int*)alloc((size_t)NT * 4 * 4);
  int*   slot_off = (int*)alloc(32 * 4);
  int*   ntiles   = (int*)alloc(256);
  int2*  desc     = (int2*)alloc((size_t)MAXTILES * 8);
  int*   tok_pad  = (int*)alloc((size_t)MAXSLOTS * 4);
  float* w_pad    = (float*)alloc((size_t)MAXSLOTS * 4);
  int*   pos_list = (int*)alloc((size_t)NT * 4 * 4);
  size_t y_off = off;
  u16* y = (u16*)alloc((size_t)MAXSLOTS * DDIM * 2);
  size_t h_off_y = off;
  (void)in_sizes; (void)n_in; (void)ws_size;

  // ---- adaptive workspace sizing: h chunk rows + mode ----
  const size_t per_row = (size_t)HPAD * 2;
  bool ymode;
  size_t h_off, rows_avail;
  size_t avail_y = (ws_size > h_off_y) ? (ws_size - h_off_y) : 0;
  if (avail_y / per_row >= 10624) {     // y + >= 1/8 of slots fits
    ymode = true; h_off = h_off_y; rows_avail = avail_y / per_row;
  } else {                              // reclaim y space, atomic mode
    ymode = false; h_off = y_off;
    size_t avail_a = (ws_size > y_off) ? (ws_size - y_off) : 0;
    rows_avail = avail_a / per_row;
  }
  int CS;
  if (rows_avail >= (size_t)MAXSLOTS) CS = MAXSLOTS;
  else CS = (int)((rows_avail / 128) * 128);
  if (CS < 128) CS = 128;
  int NCH = (MAXSLOTS + CS - 1) / CS;
  u16* h = (u16*)(ws + h_off);

  hipMemsetAsync(counts, 0, 64 * 4, stream);
  hipMemsetAsync(tok_pad, 0, (size_t)MAXSLOTS * 4, stream);
  hipMemsetAsync(w_pad, 0, (size_t)MAXSLOTS * 4, stream);
  if (!ymode) hipMemsetAsync(out, 0, (size_t)out_size * 4, stream);

  int n8 = NT * DDIM / 8;
  convert_x_kernel<<<n8 / 256, 256, 0, stream>>>(x, x_bf, n8);

  dim3 tb(32, 8);
  transpose12_kernel<<<dim3(HPAD / 32, DDIM / 32, NEXP), tb, 0, stream>>>(w1, w1t);
  transpose12_kernel<<<dim3(HPAD / 32, DDIM / 32, NEXP), tb, 0, stream>>>(w2, w2t);
  transpose12_kernel<<<dim3(HPAD / 32, DDIM / 32, 1),    tb, 0, stream>>>(sw1, sw1t);
  transpose12_kernel<<<dim3(HPAD / 32, DDIM / 32, 1),    tb, 0, stream>>>(sw2, sw2t);
  transpose3_kernel<<<dim3(DDIM / 32, HPAD / 32, NEXP),  tb, 0, stream>>>(w3, w3t);
  transpose3_kernel<<<dim3(DDIM / 32, HPAD / 32, 1),     tb, 0, stream>>>(sw3, sw3t);

  routing_kernel<<<NT, 64, 0, stream>>>(x, gate_w, rbias, counts, top_e, top_w, top_pos);
  finalize_kernel<<<1, 64, 0, stream>>>(counts, slot_off, ntiles, desc);
  scatter_kernel<<<NT / 256, 256, 0, stream>>>(top_e, top_w, top_pos, slot_off,
                                               tok_pad, w_pad, pos_list);

  for (int c = 0; c < NCH; ++c) {
    int lo = c * CS, hi = lo + CS;
    gemm1_kernel<<<dim3(MAXTILES, HPAD / 64), 512, 0, stream>>>(
        x_bf, w1t, w2t, sw1t, sw2t, ntiles, desc, tok_pad, h, lo, hi);
    if (ymode)
      gemm2_kernel<true><<<dim3(MAXTILES, DDIM / 128), 512, 0, stream>>>(
          h, w3t, sw3t, ntiles, desc, tok_pad, w_pad, y, out, lo, hi);
    else
      gemm2_kernel<false><<<dim3(MAXTILES, DDIM / 128), 512, 0, stream>>>(
          h, w3t, sw3t, ntiles, desc, tok_pad, w_pad, y, out, lo, hi);
  }
  if (ymode) reduce_kernel<<<NT, 128, 0, stream>>>(y, pos_list, slot_off, out);
}

// Round 4
// 1441.030 us; speedup vs baseline: 1.7505x; 1.5789x over previous
//
#include <hip/hip_runtime.h>

#define NT    16384
#define DDIM  512
#define HDIM  1365
#define HPAD  1408
#define NEXP  16
#define BK    64
#define BM    256
#define MAXTILES 336     // 272 routed + 64 shared
#define MAXSLOTS 86016   // 336 * 256

typedef unsigned short u16;
typedef unsigned int   u32;
typedef __attribute__((ext_vector_type(8))) __bf16 bf16x8;
typedef __attribute__((ext_vector_type(4))) float  f32x4;
typedef __attribute__((address_space(3))) void lds_void;
typedef __attribute__((address_space(1))) void glb_void;

__device__ __forceinline__ u16 f2bf(float f) {
  union { float f; u32 u; } v; v.f = f;
  u32 u = v.u;
  u += 0x7fffu + ((u >> 16) & 1u);
  return (u16)(u >> 16);
}

__device__ __forceinline__ float bf2f(u16 b) {
  union { u32 u; float f; } v; v.u = ((u32)b) << 16;
  return v.f;
}

__device__ __forceinline__ f32x4 mfma16(bf16x8 a, bf16x8 b, f32x4 c) {
  return __builtin_amdgcn_mfma_f32_16x16x32_bf16(a, b, c, 0, 0, 0);
}

__device__ __forceinline__ void gload16(const u16* g, u16* l) {
  __builtin_amdgcn_global_load_lds((const glb_void*)g, (lds_void*)l, 16, 0, 0);
}

// swizzled LDS fragment read: tile is [rows][64] u16, row stride 128B
__device__ __forceinline__ bf16x8 lds_frag(const u16* base, int row, int e0) {
  int b = ((row << 7) + (e0 << 1)) ^ ((row & 7) << 4);
  return *(const bf16x8*)((const char*)base + b);
}

// XCD-aware bijective tile swizzle (MAXTILES = 336 = 8*42)
__device__ __forceinline__ int tile_swz(int bid) {
  return (bid & 7) * (MAXTILES / 8) + (bid >> 3);
}

// ---------------- x fp32 -> bf16 ----------------
__global__ void convert_x_kernel(const float* __restrict__ in, u16* __restrict__ out, int n8) {
  int i = blockIdx.x * 256 + threadIdx.x;
  if (i >= n8) return;
  float4 a = ((const float4*)in)[2 * i];
  float4 b = ((const float4*)in)[2 * i + 1];
  u16 r[8] = {f2bf(a.x), f2bf(a.y), f2bf(a.z), f2bf(a.w),
              f2bf(b.x), f2bf(b.y), f2bf(b.z), f2bf(b.w)};
  ((uint4*)out)[i] = *(const uint4*)r;
}

// ---------- w1/w2 (E,D,H) fp32 -> (E,HPAD,D) bf16, zero-padded ----------
__global__ void transpose12_kernel(const float* __restrict__ in, u16* __restrict__ out) {
  __shared__ float tile[32][33];
  int e = blockIdx.z;
  int h0 = blockIdx.x * 32, d0 = blockIdx.y * 32;
  int tx = threadIdx.x, ty = threadIdx.y;
#pragma unroll
  for (int r = 0; r < 4; ++r) {
    int d = d0 + ty + r * 8, h = h0 + tx;
    float v = (h < HDIM) ? in[((size_t)e * DDIM + d) * HDIM + h] : 0.f;
    tile[ty + r * 8][tx] = v;
  }
  __syncthreads();
#pragma unroll
  for (int r = 0; r < 4; ++r) {
    int h = h0 + ty + r * 8, d = d0 + tx;
    out[((size_t)e * HPAD + h) * DDIM + d] = f2bf(tile[tx][ty + r * 8]);
  }
}

// ---------- w3 (E,H,D) fp32 -> (E,D,HPAD) bf16, zero-padded ----------
__global__ void transpose3_kernel(const float* __restrict__ in, u16* __restrict__ out) {
  __shared__ float tile[32][33];
  int e = blockIdx.z;
  int d0 = blockIdx.x * 32, h0 = blockIdx.y * 32;
  int tx = threadIdx.x, ty = threadIdx.y;
#pragma unroll
  for (int r = 0; r < 4; ++r) {
    int h = h0 + ty + r * 8, d = d0 + tx;
    float v = (h < HDIM) ? in[((size_t)e * HDIM + h) * DDIM + d] : 0.f;
    tile[ty + r * 8][tx] = v;
  }
  __syncthreads();
#pragma unroll
  for (int r = 0; r < 4; ++r) {
    int d = d0 + ty + r * 8, h = h0 + tx;
    out[((size_t)e * DDIM + d) * HPAD + h] = f2bf(tile[tx][ty + r * 8]);
  }
}

// ---------------- R1: logits, top-4, softmax (no atomics) ----------------
__global__ void routing_kernel(const float* __restrict__ x, const float* __restrict__ gw,
                               const float* __restrict__ rbias,
                               int* __restrict__ top_e, float* __restrict__ top_w) {
  int t = blockIdx.x;
  int lane = threadIdx.x;
  float acc[NEXP];
#pragma unroll
  for (int e = 0; e < NEXP; ++e) acc[e] = 0.f;
  const float* xr = x + (size_t)t * DDIM;
  for (int d = lane; d < DDIM; d += 64) {
    float xv = xr[d];
    const float4* g4 = (const float4*)(gw + d * NEXP);
    float4 g0 = g4[0], g1 = g4[1], g2 = g4[2], g3 = g4[3];
    acc[0] += xv * g0.x; acc[1] += xv * g0.y; acc[2]  += xv * g0.z; acc[3]  += xv * g0.w;
    acc[4] += xv * g1.x; acc[5] += xv * g1.y; acc[6]  += xv * g1.z; acc[7]  += xv * g1.w;
    acc[8] += xv * g2.x; acc[9] += xv * g2.y; acc[10] += xv * g2.z; acc[11] += xv * g2.w;
    acc[12] += xv * g3.x; acc[13] += xv * g3.y; acc[14] += xv * g3.z; acc[15] += xv * g3.w;
  }
#pragma unroll
  for (int e = 0; e < NEXP; ++e) {
    float v = acc[e];
#pragma unroll
    for (int off = 32; off; off >>= 1) v += __shfl_xor(v, off);
    acc[e] = v + rbias[e];
  }
  if (lane == 0) {
    int sel[4]; float sv[4];
    unsigned used = 0;
#pragma unroll
    for (int i = 0; i < 4; ++i) {
      float best = -1e30f; int bi = 0;
#pragma unroll
      for (int e = 0; e < NEXP; ++e) {
        bool ok = !((used >> e) & 1u) && acc[e] > best;
        best = ok ? acc[e] : best;
        bi   = ok ? e : bi;
      }
      used |= 1u << bi; sel[i] = bi; sv[i] = best;
    }
    float m = sv[0];
    float ex[4]; float s = 0.f;
#pragma unroll
    for (int i = 0; i < 4; ++i) { ex[i] = __expf(sv[i] - m); s += ex[i]; }
    float inv = 1.f / s;
#pragma unroll
    for (int i = 0; i < 4; ++i) {
      top_e[t * 4 + i] = sel[i];
      top_w[t * 4 + i] = ex[i] * inv;
    }
  }
}

// ---------------- R2: hierarchical counting + rank (16 blocks x 1024) ----------------
__global__ __launch_bounds__(1024) void rank_kernel(const int* __restrict__ top_e,
                                                    int* __restrict__ counts,
                                                    int* __restrict__ top_pos) {
  __shared__ int hist[NEXP], base[NEXP];
  int tid = threadIdx.x;
  int t = blockIdx.x * 1024 + tid;
  if (tid < NEXP) hist[tid] = 0;
  __syncthreads();
  int e4[4], r4[4];
#pragma unroll
  for (int i = 0; i < 4; ++i) {
    e4[i] = top_e[t * 4 + i];
    r4[i] = atomicAdd(&hist[e4[i]], 1);
  }
  __syncthreads();
  if (tid < NEXP) base[tid] = atomicAdd(&counts[tid], hist[tid]);
  __syncthreads();
#pragma unroll
  for (int i = 0; i < 4; ++i) top_pos[t * 4 + i] = base[e4[i]] + r4[i];
}

// ---------------- finalize: padded slot offsets + tile descriptors ----------------
__global__ void finalize_kernel(const int* __restrict__ counts, int* __restrict__ slot_off,
                                int* __restrict__ ntiles, int2* __restrict__ desc) {
  if (threadIdx.x != 0) return;
  int off = 0, td = 0;
  for (int e = 0; e < 17; ++e) {
    int c = (e == 16) ? NT : counts[e];
    slot_off[e] = off;
    int nt = (c + BM - 1) / BM;
    for (int i = 0; i < nt; ++i) { desc[td] = make_int2(e, off + i * BM); ++td; }
    off += nt * BM;
  }
  slot_off[17] = off;
  *ntiles = td;
}

// ---------------- scatter: per-slot token / weight, per-token slot list ----------------
__global__ void scatter_kernel(const int* __restrict__ top_e, const float* __restrict__ top_w,
                               const int* __restrict__ top_pos, const int* __restrict__ slot_off,
                               int* __restrict__ tok_pad, float* __restrict__ w_pad,
                               int* __restrict__ pos_list) {
  int t = blockIdx.x * 256 + threadIdx.x;
  if (t >= NT) return;
#pragma unroll
  for (int i = 0; i < 4; ++i) {
    int e = top_e[t * 4 + i];
    int slot = slot_off[e] + top_pos[t * 4 + i];
    tok_pad[slot] = t;
    w_pad[slot] = top_w[t * 4 + i];
    pos_list[t * 4 + i] = slot;
  }
  int sh = slot_off[16] + t;
  tok_pad[sh] = t;
  w_pad[sh] = 1.f;
}

// ---------------- K1: grouped GEMM1 + SwiGLU -> h bf16 (slot chunk [lo,hi)) ----------
// tile: 256 slots x 128 h-cols. B tile [256][BK]: 16-row groups alternate W1/W2 so that
// each thread's acc[mf][2hc] (g) and acc[mf][2hc+1] (u) cover the SAME h-col.
__global__ __launch_bounds__(512, 2) void gemm1_kernel(
    const u16* __restrict__ x_bf, const u16* __restrict__ w1t, const u16* __restrict__ w2t,
    const u16* __restrict__ sw1t, const u16* __restrict__ sw2t,
    const int* __restrict__ ntiles, const int2* __restrict__ desc,
    const int* __restrict__ tok_pad, u16* __restrict__ h, int lo, int hi) {
  int bx = tile_swz(blockIdx.x);
  if (bx >= *ntiles) return;
  int2 de = desc[bx];
  int e = de.x, m0 = de.y;
  if (m0 < lo || m0 >= hi) return;
  int n0 = blockIdx.y * 128;
  const u16* W1 = (e == 16) ? sw1t : (w1t + (size_t)e * HPAD * DDIM);
  const u16* W2 = (e == 16) ? sw2t : (w2t + (size_t)e * HPAD * DDIM);

  __shared__ u16 smem[65536];            // 128 KiB: A dbuf 64K | B dbuf 64K
  u16* xs = smem;                         // 2 x [256][64]
  u16* bs = smem + 32768;

  int tid = threadIdx.x, w = tid >> 6, lane = tid & 63;
  int wm = w >> 2, wn = w & 3, lr = lane & 15, lk = lane >> 4;
  int lrow = lane >> 3, lch = lane & 7;

  const u16* ags[4]; const u16* bgs[4];
#pragma unroll
  for (int p = 0; p < 4; ++p) {
    int rw = p * 64 + w * 8 + lrow;                 // tile row 0..255
    int ce = ((lch ^ (rw & 7)) << 3);               // pre-swizzled source elem
    ags[p] = x_bf + (size_t)tok_pad[m0 + rw] * DDIM + ce;
    int grp = rw >> 4;
    const u16* Wsrc = (grp & 1) ? W2 : W1;
    int hrow = n0 + ((grp >> 1) << 4) + (rw & 15);
    bgs[p] = Wsrc + (size_t)hrow * DDIM + ce;
  }

  auto stage = [&](int ks, int buf) {
    int k0 = ks * BK;
#pragma unroll
    for (int p = 0; p < 4; ++p) {
      int rb = (p * 64 + w * 8) << 6;
      gload16(ags[p] + k0, xs + buf * 16384 + rb);
      gload16(bgs[p] + k0, bs + buf * 16384 + rb);
    }
  };

  f32x4 acc[8][4] = {};
  stage(0, 0);
  __syncthreads();

  for (int ks = 0; ks < DDIM / BK; ++ks) {
    int cur = ks & 1;
    if (ks + 1 < DDIM / BK) stage(ks + 1, cur ^ 1);
    const u16* xb = xs + cur * 16384;
    const u16* bb = bs + cur * 16384;
#pragma unroll
    for (int kf = 0; kf < 2; ++kf) {
      int e0 = kf * 32 + lk * 8;
      bf16x8 bfr[4];
#pragma unroll
      for (int nf = 0; nf < 4; ++nf)
        bfr[nf] = lds_frag(bb, wn * 64 + nf * 16 + lr, e0);
#pragma unroll
      for (int mf = 0; mf < 8; ++mf) {
        bf16x8 a = lds_frag(xb, wm * 128 + mf * 16 + lr, e0);
#pragma unroll
        for (int nf = 0; nf < 4; ++nf)
          acc[mf][nf] = mfma16(a, bfr[nf], acc[mf][nf]);
      }
    }
    __syncthreads();
  }

  // epilogue: SwiGLU pairs are register-local; store h
#pragma unroll
  for (int mf = 0; mf < 8; ++mf)
#pragma unroll
    for (int hc = 0; hc < 2; ++hc)
#pragma unroll
      for (int j = 0; j < 4; ++j) {
        float g = acc[mf][hc * 2][j], u = acc[mf][hc * 2 + 1][j];
        float hv = g * u / (1.f + __expf(-g));
        int row = wm * 128 + mf * 16 + lk * 4 + j;
        h[(size_t)(m0 - lo + row) * HPAD + n0 + wn * 32 + hc * 16 + lr] = f2bf(hv);
      }
}

// ---------------- K2: grouped GEMM2, weighted (slot chunk [lo,hi)) ----------------
// tile 256 slots x 256 d-cols, K = HPAD (22 steps). YMODE: y bf16; else atomicAdd out.
template <bool YMODE>
__global__ __launch_bounds__(512, 2) void gemm2_kernel(
    const u16* __restrict__ h, const u16* __restrict__ w3t, const u16* __restrict__ sw3t,
    const int* __restrict__ ntiles, const int2* __restrict__ desc,
    const int* __restrict__ tok_pad, const float* __restrict__ w_pad,
    u16* __restrict__ y, float* __restrict__ out, int lo, int hi) {
  int bx = tile_swz(blockIdx.x);
  if (bx >= *ntiles) return;
  int2 de = desc[bx];
  int e = de.x, m0 = de.y;
  if (m0 < lo || m0 >= hi) return;
  int n0 = blockIdx.y * 256;
  const u16* W3 = (e == 16) ? sw3t : (w3t + (size_t)e * DDIM * HPAD);

  __shared__ u16 smem[65536];
  __shared__ float swl[BM];
  u16* hs = smem;
  u16* ws3 = smem + 32768;

  int tid = threadIdx.x, w = tid >> 6, lane = tid & 63;
  int wm = w >> 2, wn = w & 3, lr = lane & 15, lk = lane >> 4;
  int lrow = lane >> 3, lch = lane & 7;

  if (tid < BM) swl[tid] = w_pad[m0 + tid];

  const u16* ags[4]; const u16* bgs[4];
#pragma unroll
  for (int p = 0; p < 4; ++p) {
    int rw = p * 64 + w * 8 + lrow;
    int ce = ((lch ^ (rw & 7)) << 3);
    ags[p] = h + (size_t)(m0 - lo + rw) * HPAD + ce;
    bgs[p] = W3 + (size_t)(n0 + rw) * HPAD + ce;
  }

  auto stage = [&](int ks, int buf) {
    int k0 = ks * BK;
#pragma unroll
    for (int p = 0; p < 4; ++p) {
      int rb = (p * 64 + w * 8) << 6;
      gload16(ags[p] + k0, hs + buf * 16384 + rb);
      gload16(bgs[p] + k0, ws3 + buf * 16384 + rb);
    }
  };

  f32x4 acc[8][4] = {};
  stage(0, 0);
  __syncthreads();

  for (int ks = 0; ks < HPAD / BK; ++ks) {
    int cur = ks & 1;
    if (ks + 1 < HPAD / BK) stage(ks + 1, cur ^ 1);
    const u16* hb = hs + cur * 16384;
    const u16* wb = ws3 + cur * 16384;
#pragma unroll
    for (int kf = 0; kf < 2; ++kf) {
      int e0 = kf * 32 + lk * 8;
      bf16x8 bfr[4];
#pragma unroll
      for (int nf = 0; nf < 4; ++nf)
        bfr[nf] = lds_frag(wb, wn * 64 + nf * 16 + lr, e0);
#pragma unroll
      for (int mf = 0; mf < 8; ++mf) {
        bf16x8 a = lds_frag(hb, wm * 128 + mf * 16 + lr, e0);
#pragma unroll
        for (int nf = 0; nf < 4; ++nf)
          acc[mf][nf] = mfma16(a, bfr[nf], acc[mf][nf]);
      }
    }
    __syncthreads();
  }

#pragma unroll
  for (int mf = 0; mf < 8; ++mf)
#pragma unroll
    for (int j = 0; j < 4; ++j) {
      int row = wm * 128 + mf * 16 + lk * 4 + j;
      float wv = swl[row];
      if constexpr (YMODE) {
        u16* yrow = y + (size_t)(m0 + row) * DDIM + n0;
#pragma unroll
        for (int nf = 0; nf < 4; ++nf)
          yrow[wn * 64 + nf * 16 + lr] = f2bf(acc[mf][nf][j] * wv);
      } else {
        float* orow = out + (size_t)tok_pad[m0 + row] * DDIM + n0;
#pragma unroll
        for (int nf = 0; nf < 4; ++nf)
          atomicAdd(&orow[wn * 64 + nf * 16 + lr], acc[mf][nf][j] * wv);
      }
    }
}

// ---------------- reduce: out[t] = y_shared + sum of 4 routed y ----------------
__global__ void reduce_kernel(const u16* __restrict__ y, const int* __restrict__ pos_list,
                              const int* __restrict__ slot_off, float* __restrict__ out) {
  int t = blockIdx.x;
  int c = threadIdx.x;   // 128 threads, 4 elems each
  int4 pl = ((const int4*)pos_list)[t];
  int sh = slot_off[16] + t;
  ushort4 a = ((const ushort4*)(y + (size_t)sh * DDIM))[c];
  ushort4 b = ((const ushort4*)(y + (size_t)pl.x * DDIM))[c];
  ushort4 d = ((const ushort4*)(y + (size_t)pl.y * DDIM))[c];
  ushort4 e = ((const ushort4*)(y + (size_t)pl.z * DDIM))[c];
  ushort4 f = ((const ushort4*)(y + (size_t)pl.w * DDIM))[c];
  float4 s;
  s.x = bf2f(a.x) + bf2f(b.x) + bf2f(d.x) + bf2f(e.x) + bf2f(f.x);
  s.y = bf2f(a.y) + bf2f(b.y) + bf2f(d.y) + bf2f(e.y) + bf2f(f.y);
  s.z = bf2f(a.z) + bf2f(b.z) + bf2f(d.z) + bf2f(e.z) + bf2f(f.z);
  s.w = bf2f(a.w) + bf2f(b.w) + bf2f(d.w) + bf2f(e.w) + bf2f(f.w);
  ((float4*)(out + (size_t)t * DDIM))[c] = s;
}

extern "C" void kernel_launch(void* const* d_in, const int* in_sizes, int n_in,
                              void* d_out, int out_size, void* d_ws, size_t ws_size,
                              hipStream_t stream) {
  const float* x      = (const float*)d_in[0];
  const float* gate_w = (const float*)d_in[1];
  const float* rbias  = (const float*)d_in[2];
  const float* w1     = (const float*)d_in[3];
  const float* w2     = (const float*)d_in[4];
  const float* w3     = (const float*)d_in[5];
  const float* sw1    = (const float*)d_in[6];
  const float* sw2    = (const float*)d_in[7];
  const float* sw3    = (const float*)d_in[8];
  float* out = (float*)d_out;

  char* ws = (char*)d_ws;
  size_t off = 0;
  auto alloc = [&](size_t bytes) -> char* {
    char* p = ws + off;
    off += (bytes + 255) & ~(size_t)255;
    return p;
  };
  u16* x_bf  = (u16*)alloc((size_t)NT * DDIM * 2);
  u16* w1t   = (u16*)alloc((size_t)NEXP * HPAD * DDIM * 2);
  u16* w2t   = (u16*)alloc((size_t)NEXP * HPAD * DDIM * 2);
  u16* w3t   = (u16*)alloc((size_t)NEXP * DDIM * HPAD * 2);
  u16* sw1t  = (u16*)alloc((size_t)HPAD * DDIM * 2);
  u16* sw2t  = (u16*)alloc((size_t)HPAD * DDIM * 2);
  u16* sw3t  = (u16*)alloc((size_t)DDIM * HPAD * 2);
  int*   counts   = (int*)alloc(64 * 4);
  int*   top_e    = (int*)alloc((size_t)NT * 4 * 4);
  float* top_w    = (float*)alloc((size_t)NT * 4 * 4);
  int*   top_pos  = (int*)alloc((size_t)NT * 4 * 4);
  int*   slot_off = (int*)alloc(32 * 4);
  int*   ntiles   = (int*)alloc(256);
  int2*  desc     = (int2*)alloc((size_t)MAXTILES * 8);
  int*   tok_pad  = (int*)alloc((size_t)MAXSLOTS * 4);
  float* w_pad    = (float*)alloc((size_t)MAXSLOTS * 4);
  int*   pos_list = (int*)alloc((size_t)NT * 4 * 4);
  size_t y_off = off;
  u16* y = (u16*)alloc((size_t)MAXSLOTS * DDIM * 2);
  size_t h_off_y = off;
  (void)in_sizes; (void)n_in; (void)ws_size;

  // ---- adaptive workspace sizing: h chunk rows + mode ----
  const size_t per_row = (size_t)HPAD * 2;
  bool ymode;
  size_t h_off, rows_avail;
  size_t avail_y = (ws_size > h_off_y) ? (ws_size - h_off_y) : 0;
  if (avail_y / per_row >= 10752) {     // y + >= 1/8 of slots fits
    ymode = true; h_off = h_off_y; rows_avail = avail_y / per_row;
  } else {                              // reclaim y space, atomic mode
    ymode = false; h_off = y_off;
    size_t avail_a = (ws_size > y_off) ? (ws_size - y_off) : 0;
    rows_avail = avail_a / per_row;
  }
  int CS;
  if (rows_avail >= (size_t)MAXSLOTS) CS = MAXSLOTS;
  else CS = (int)((rows_avail / BM) * BM);
  if (CS < BM) CS = BM;
  int NCH = (MAXSLOTS + CS - 1) / CS;
  u16* h = (u16*)(ws + h_off);

  hipMemsetAsync(counts, 0, 64 * 4, stream);
  hipMemsetAsync(tok_pad, 0, (size_t)MAXSLOTS * 4, stream);
  hipMemsetAsync(w_pad, 0, (size_t)MAXSLOTS * 4, stream);
  if (!ymode) hipMemsetAsync(out, 0, (size_t)out_size * 4, stream);

  int n8 = NT * DDIM / 8;
  convert_x_kernel<<<n8 / 256, 256, 0, stream>>>(x, x_bf, n8);

  dim3 tb(32, 8);
  transpose12_kernel<<<dim3(HPAD / 32, DDIM / 32, NEXP), tb, 0, stream>>>(w1, w1t);
  transpose12_kernel<<<dim3(HPAD / 32, DDIM / 32, NEXP), tb, 0, stream>>>(w2, w2t);
  transpose12_kernel<<<dim3(HPAD / 32, DDIM / 32, 1),    tb, 0, stream>>>(sw1, sw1t);
  transpose12_kernel<<<dim3(HPAD / 32, DDIM / 32, 1),    tb, 0, stream>>>(sw2, sw2t);
  transpose3_kernel<<<dim3(DDIM / 32, HPAD / 32, NEXP),  tb, 0, stream>>>(w3, w3t);
  transpose3_kernel<<<dim3(DDIM / 32, HPAD / 32, 1),     tb, 0, stream>>>(sw3, sw3t);

  routing_kernel<<<NT, 64, 0, stream>>>(x, gate_w, rbias, top_e, top_w);
  rank_kernel<<<NT / 1024, 1024, 0, stream>>>(top_e, counts, top_pos);
  finalize_kernel<<<1, 64, 0, stream>>>(counts, slot_off, ntiles, desc);
  scatter_kernel<<<NT / 256, 256, 0, stream>>>(top_e, top_w, top_pos, slot_off,
                                               tok_pad, w_pad, pos_list);

  for (int c = 0; c < NCH; ++c) {
    int lo = c * CS, hi = lo + CS;
    gemm1_kernel<<<dim3(MAXTILES, HPAD / 128), 512, 0, stream>>>(
        x_bf, w1t, w2t, sw1t, sw2t, ntiles, desc, tok_pad, h, lo, hi);
    if (ymode)
      gemm2_kernel<true><<<dim3(MAXTILES, DDIM / 256), 512, 0, stream>>>(
          h, w3t, sw3t, ntiles, desc, tok_pad, w_pad, y, out, lo, hi);
    else
      gemm2_kernel<false><<<dim3(MAXTILES, DDIM / 256), 512, 0, stream>>>(
          h, w3t, sw3t, ntiles, desc, tok_pad, w_pad, y, out, lo, hi);
  }
  if (ymode) reduce_kernel<<<NT, 128, 0, stream>>>(y, pos_list, slot_off, out);
}

// Round 5
// 672.770 us; speedup vs baseline: 3.7494x; 2.1419x over previous
//
#include <hip/hip_runtime.h>

#define NT    16384
#define DDIM  512
#define HDIM  1365
#define HPAD  1408
#define NEXP  16
#define BK    64
#define BM    128
#define MAXTILES 656
#define MAXSLOTS 83968   // 656 * 128

typedef unsigned short u16;
typedef unsigned int   u32;
typedef __attribute__((ext_vector_type(8))) __bf16 bf16x8;
typedef __attribute__((ext_vector_type(4))) float  f32x4;
typedef __attribute__((address_space(3))) void lds_void;
typedef __attribute__((address_space(1))) void glb_void;

__device__ __forceinline__ u16 f2bf(float f) {
  union { float f; u32 u; } v; v.f = f;
  u32 u = v.u;
  u += 0x7fffu + ((u >> 16) & 1u);
  return (u16)(u >> 16);
}

__device__ __forceinline__ float bf2f(u16 b) {
  union { u32 u; float f; } v; v.u = ((u32)b) << 16;
  return v.f;
}

__device__ __forceinline__ f32x4 mfma16(bf16x8 a, bf16x8 b, f32x4 c) {
  return __builtin_amdgcn_mfma_f32_16x16x32_bf16(a, b, c, 0, 0, 0);
}

__device__ __forceinline__ void gload16(const u16* g, u16* l) {
  __builtin_amdgcn_global_load_lds((const glb_void*)g, (lds_void*)l, 16, 0, 0);
}

// swizzled LDS fragment read: tile is [rows][64] u16, row stride 128B
__device__ __forceinline__ bf16x8 lds_frag(const u16* base, int row, int e0) {
  int b = ((row << 7) + (e0 << 1)) ^ ((row & 7) << 4);
  return *(const bf16x8*)((const char*)base + b);
}

// m204 bijective XCD swizzle for arbitrary n (bid < n)
__device__ __forceinline__ int swz_n(int bid, int n) {
  int q = n >> 3, r = n & 7;
  int xcd = bid & 7, j = bid >> 3;
  return (xcd < r ? xcd * (q + 1) : r * (q + 1) + (xcd - r) * q) + j;
}

// ---------------- x fp32 -> bf16 ----------------
__global__ void convert_x_kernel(const float* __restrict__ in, u16* __restrict__ out, int n8) {
  int i = blockIdx.x * 256 + threadIdx.x;
  if (i >= n8) return;
  float4 a = ((const float4*)in)[2 * i];
  float4 b = ((const float4*)in)[2 * i + 1];
  u16 r[8] = {f2bf(a.x), f2bf(a.y), f2bf(a.z), f2bf(a.w),
              f2bf(b.x), f2bf(b.y), f2bf(b.z), f2bf(b.w)};
  ((uint4*)out)[i] = *(const uint4*)r;
}

// ---------- w1/w2 (E,D,H) fp32 -> (E,HPAD,D) bf16, zero-padded ----------
__global__ void transpose12_kernel(const float* __restrict__ in, u16* __restrict__ out) {
  __shared__ float tile[32][33];
  int e = blockIdx.z;
  int h0 = blockIdx.x * 32, d0 = blockIdx.y * 32;
  int tx = threadIdx.x, ty = threadIdx.y;
#pragma unroll
  for (int r = 0; r < 4; ++r) {
    int d = d0 + ty + r * 8, h = h0 + tx;
    float v = (h < HDIM) ? in[((size_t)e * DDIM + d) * HDIM + h] : 0.f;
    tile[ty + r * 8][tx] = v;
  }
  __syncthreads();
#pragma unroll
  for (int r = 0; r < 4; ++r) {
    int h = h0 + ty + r * 8, d = d0 + tx;
    out[((size_t)e * HPAD + h) * DDIM + d] = f2bf(tile[tx][ty + r * 8]);
  }
}

// ---------- w3 (E,H,D) fp32 -> (E,D,HPAD) bf16, zero-padded ----------
__global__ void transpose3_kernel(const float* __restrict__ in, u16* __restrict__ out) {
  __shared__ float tile[32][33];
  int e = blockIdx.z;
  int d0 = blockIdx.x * 32, h0 = blockIdx.y * 32;
  int tx = threadIdx.x, ty = threadIdx.y;
#pragma unroll
  for (int r = 0; r < 4; ++r) {
    int h = h0 + ty + r * 8, d = d0 + tx;
    float v = (h < HDIM) ? in[((size_t)e * HDIM + h) * DDIM + d] : 0.f;
    tile[ty + r * 8][tx] = v;
  }
  __syncthreads();
#pragma unroll
  for (int r = 0; r < 4; ++r) {
    int d = d0 + ty + r * 8, h = h0 + tx;
    out[((size_t)e * DDIM + d) * HPAD + h] = f2bf(tile[tx][ty + r * 8]);
  }
}

// ---------------- R1: logits, top-4, softmax (8 waves/block, gw in LDS) ----------------
__global__ __launch_bounds__(512) void routing_kernel(
    const float* __restrict__ x, const float* __restrict__ gw,
    const float* __restrict__ rbias,
    int* __restrict__ top_e, float* __restrict__ top_w) {
  __shared__ float gwT[NEXP * DDIM];   // 32 KiB, transposed [e][d]
  int tid = threadIdx.x;
  for (int i = tid; i < NEXP * DDIM; i += 512) {
    int d = i >> 4, e = i & 15;
    gwT[e * DDIM + d] = gw[i];
  }
  __syncthreads();
  int w = tid >> 6, lane = tid & 63;
  int t = blockIdx.x * 8 + w;
  const float* xr = x + (size_t)t * DDIM;
  float xv[8];
#pragma unroll
  for (int k = 0; k < 8; ++k) xv[k] = xr[lane + (k << 6)];
  float acc[NEXP];
#pragma unroll
  for (int e = 0; e < NEXP; ++e) {
    const float* ge = gwT + e * DDIM + lane;
    float s = 0.f;
#pragma unroll
    for (int k = 0; k < 8; ++k) s += xv[k] * ge[k << 6];
#pragma unroll
    for (int off = 32; off; off >>= 1) s += __shfl_xor(s, off);
    acc[e] = s + rbias[e];
  }
  if (lane == 0) {
    int sel[4]; float sv[4];
    unsigned used = 0;
#pragma unroll
    for (int i = 0; i < 4; ++i) {
      float best = -1e30f; int bi = 0;
#pragma unroll
      for (int e = 0; e < NEXP; ++e) {
        bool ok = !((used >> e) & 1u) && acc[e] > best;
        best = ok ? acc[e] : best;
        bi   = ok ? e : bi;
      }
      used |= 1u << bi; sel[i] = bi; sv[i] = best;
    }
    float m = sv[0];
    float ex[4]; float s = 0.f;
#pragma unroll
    for (int i = 0; i < 4; ++i) { ex[i] = __expf(sv[i] - m); s += ex[i]; }
    float inv = 1.f / s;
#pragma unroll
    for (int i = 0; i < 4; ++i) {
      top_e[t * 4 + i] = sel[i];
      top_w[t * 4 + i] = ex[i] * inv;
    }
  }
}

// ---------------- R2: hierarchical counting + rank (16 blocks x 1024) ----------------
__global__ __launch_bounds__(1024) void rank_kernel(const int* __restrict__ top_e,
                                                    int* __restrict__ counts,
                                                    int* __restrict__ top_pos) {
  __shared__ int hist[NEXP], base[NEXP];
  int tid = threadIdx.x;
  int t = blockIdx.x * 1024 + tid;
  if (tid < NEXP) hist[tid] = 0;
  __syncthreads();
  int e4[4], r4[4];
#pragma unroll
  for (int i = 0; i < 4; ++i) {
    e4[i] = top_e[t * 4 + i];
    r4[i] = atomicAdd(&hist[e4[i]], 1);
  }
  __syncthreads();
  if (tid < NEXP) base[tid] = atomicAdd(&counts[tid], hist[tid]);
  __syncthreads();
#pragma unroll
  for (int i = 0; i < 4; ++i) top_pos[t * 4 + i] = base[e4[i]] + r4[i];
}

// ---------------- finalize: padded slot offsets + tile descriptors ----------------
__global__ void finalize_kernel(const int* __restrict__ counts, int* __restrict__ slot_off,
                                int* __restrict__ ntiles, int2* __restrict__ desc) {
  if (threadIdx.x != 0) return;
  int off = 0, td = 0;
  for (int e = 0; e < 17; ++e) {
    int c = (e == 16) ? NT : counts[e];
    slot_off[e] = off;
    int nt = (c + BM - 1) / BM;
    for (int i = 0; i < nt; ++i) { desc[td] = make_int2(e, off + i * BM); ++td; }
    off += nt * BM;
  }
  slot_off[17] = off;
  *ntiles = td;
}

// ---------------- scatter: per-slot token / weight, per-token slot list ----------------
__global__ void scatter_kernel(const int* __restrict__ top_e, const float* __restrict__ top_w,
                               const int* __restrict__ top_pos, const int* __restrict__ slot_off,
                               int* __restrict__ tok_pad, float* __restrict__ w_pad,
                               int* __restrict__ pos_list) {
  int t = blockIdx.x * 256 + threadIdx.x;
  if (t >= NT) return;
#pragma unroll
  for (int i = 0; i < 4; ++i) {
    int e = top_e[t * 4 + i];
    int slot = slot_off[e] + top_pos[t * 4 + i];
    tok_pad[slot] = t;
    w_pad[slot] = top_w[t * 4 + i];
    pos_list[t * 4 + i] = slot;
  }
  int sh = slot_off[16] + t;
  tok_pad[sh] = t;
  w_pad[sh] = 1.f;
}

// ---------------- K1: grouped GEMM1 + SwiGLU -> h bf16 (m97-style) ----------------
// 256 threads = 4 waves (2m x 2n). Tile 128 slots x 64 h-cols (B rows = 128: 16-row
// groups alternate W1/W2). Single-buffered 32 KiB LDS, 2 barriers/K-step.
__global__ __launch_bounds__(256, 3) void gemm1_kernel(
    const u16* __restrict__ x_bf, const u16* __restrict__ w1t, const u16* __restrict__ w2t,
    const u16* __restrict__ sw1t, const u16* __restrict__ sw2t,
    const int* __restrict__ ntiles, const int2* __restrict__ desc,
    const int* __restrict__ tok_pad, u16* __restrict__ h, int lo, int ntc) {
  int ti = (lo >> 7) + swz_n(blockIdx.x, ntc);
  if (ti >= *ntiles) return;
  int2 de = desc[ti];
  int e = de.x, m0 = de.y;
  int n0 = blockIdx.y * 64;
  const u16* W1 = (e == 16) ? sw1t : (w1t + (size_t)e * HPAD * DDIM);
  const u16* W2 = (e == 16) ? sw2t : (w2t + (size_t)e * HPAD * DDIM);

  __shared__ u16 xs[BM * BK];   // 16 KiB
  __shared__ u16 bs[BM * BK];   // 16 KiB

  int tid = threadIdx.x, w = tid >> 6, lane = tid & 63;
  int wm = w >> 1, wn = w & 1, lr = lane & 15, lk = lane >> 4;

  const u16* ags[4]; const u16* bgs[4];
  int ce = (((lane & 7) ^ ((lane >> 3) & 7)) << 3);
#pragma unroll
  for (int p = 0; p < 4; ++p) {
    int r = w * 32 + p * 8 + (lane >> 3);
    ags[p] = x_bf + (size_t)tok_pad[m0 + r] * DDIM + ce;
    int grp = (w * 32 + p * 8) >> 4;                 // uniform per (w,p)
    const u16* Wsrc = (grp & 1) ? W2 : W1;
    int hrow = n0 + ((grp >> 1) << 4) + (r & 15);
    bgs[p] = Wsrc + (size_t)hrow * DDIM + ce;
  }

  f32x4 acc[4][4] = {};

  for (int ks = 0; ks < DDIM / BK; ++ks) {
    int k0 = ks * BK;
#pragma unroll
    for (int p = 0; p < 4; ++p) {
      gload16(ags[p] + k0, xs + ((w * 32 + p * 8) << 6));
      gload16(bgs[p] + k0, bs + ((w * 32 + p * 8) << 6));
    }
    __syncthreads();
#pragma unroll
    for (int kf = 0; kf < 2; ++kf) {
      int e0 = kf * 32 + lk * 8;
      bf16x8 bfr[4];
#pragma unroll
      for (int nf = 0; nf < 4; ++nf)
        bfr[nf] = lds_frag(bs, wn * 64 + nf * 16 + lr, e0);
#pragma unroll
      for (int mf = 0; mf < 4; ++mf) {
        bf16x8 a = lds_frag(xs, wm * 64 + mf * 16 + lr, e0);
#pragma unroll
        for (int nf = 0; nf < 4; ++nf)
          acc[mf][nf] = mfma16(a, bfr[nf], acc[mf][nf]);
      }
    }
    __syncthreads();
  }

  // epilogue: (nf, nf+1) pairs share the same h-col -> register-local SwiGLU
#pragma unroll
  for (int mf = 0; mf < 4; ++mf)
#pragma unroll
    for (int nf = 0; nf < 4; nf += 2)
#pragma unroll
      for (int j = 0; j < 4; ++j) {
        float g = acc[mf][nf][j], u = acc[mf][nf + 1][j];
        float hv = g * u / (1.f + __expf(-g));
        int row = wm * 64 + mf * 16 + lk * 4 + j;
        int hcol = n0 + wn * 32 + (nf >> 1) * 16 + lr;
        h[(size_t)(m0 - lo + row) * HPAD + hcol] = f2bf(hv);
      }
}

// ---------------- K2: grouped GEMM2, weighted (m97-style) ----------------
// tile 128 slots x 128 d-cols, K = HPAD (22 steps). YMODE: y bf16; else atomicAdd out.
template <bool YMODE>
__global__ __launch_bounds__(256, 3) void gemm2_kernel(
    const u16* __restrict__ h, const u16* __restrict__ w3t, const u16* __restrict__ sw3t,
    const int* __restrict__ ntiles, const int2* __restrict__ desc,
    const int* __restrict__ tok_pad, const float* __restrict__ w_pad,
    u16* __restrict__ y, float* __restrict__ out, int lo, int ntc) {
  int ti = (lo >> 7) + swz_n(blockIdx.x, ntc);
  if (ti >= *ntiles) return;
  int2 de = desc[ti];
  int e = de.x, m0 = de.y;
  int n0 = blockIdx.y * 128;
  const u16* W3 = (e == 16) ? sw3t : (w3t + (size_t)e * DDIM * HPAD);

  __shared__ u16 hs[BM * BK];
  __shared__ u16 ws3[BM * BK];
  __shared__ float swl[BM];

  int tid = threadIdx.x, w = tid >> 6, lane = tid & 63;
  int wm = w >> 1, wn = w & 1, lr = lane & 15, lk = lane >> 4;

  if (tid < BM) swl[tid] = w_pad[m0 + tid];

  const u16* ags[4]; const u16* bgs[4];
  int ce = (((lane & 7) ^ ((lane >> 3) & 7)) << 3);
#pragma unroll
  for (int p = 0; p < 4; ++p) {
    int r = w * 32 + p * 8 + (lane >> 3);
    ags[p] = h + (size_t)(m0 - lo + r) * HPAD + ce;
    bgs[p] = W3 + (size_t)(n0 + r) * HPAD + ce;
  }

  f32x4 acc[4][4] = {};

  for (int ks = 0; ks < HPAD / BK; ++ks) {
    int k0 = ks * BK;
#pragma unroll
    for (int p = 0; p < 4; ++p) {
      gload16(ags[p] + k0, hs + ((w * 32 + p * 8) << 6));
      gload16(bgs[p] + k0, ws3 + ((w * 32 + p * 8) << 6));
    }
    __syncthreads();
#pragma unroll
    for (int kf = 0; kf < 2; ++kf) {
      int e0 = kf * 32 + lk * 8;
      bf16x8 bfr[4];
#pragma unroll
      for (int nf = 0; nf < 4; ++nf)
        bfr[nf] = lds_frag(ws3, wn * 64 + nf * 16 + lr, e0);
#pragma unroll
      for (int mf = 0; mf < 4; ++mf) {
        bf16x8 a = lds_frag(hs, wm * 64 + mf * 16 + lr, e0);
#pragma unroll
        for (int nf = 0; nf < 4; ++nf)
          acc[mf][nf] = mfma16(a, bfr[nf], acc[mf][nf]);
      }
    }
    __syncthreads();
  }

#pragma unroll
  for (int mf = 0; mf < 4; ++mf)
#pragma unroll
    for (int j = 0; j < 4; ++j) {
      int row = wm * 64 + mf * 16 + lk * 4 + j;
      float wv = swl[row];
      if constexpr (YMODE) {
        u16* yrow = y + (size_t)(m0 + row) * DDIM + n0;
#pragma unroll
        for (int nf = 0; nf < 4; ++nf)
          yrow[wn * 64 + nf * 16 + lr] = f2bf(acc[mf][nf][j] * wv);
      } else {
        float* orow = out + (size_t)tok_pad[m0 + row] * DDIM + n0;
#pragma unroll
        for (int nf = 0; nf < 4; ++nf)
          atomicAdd(&orow[wn * 64 + nf * 16 + lr], acc[mf][nf][j] * wv);
      }
    }
}

// ---------------- reduce: out[t] = y_shared + sum of 4 routed y ----------------
__global__ void reduce_kernel(const u16* __restrict__ y, const int* __restrict__ pos_list,
                              const int* __restrict__ slot_off, float* __restrict__ out) {
  int t = blockIdx.x;
  int c = threadIdx.x;   // 128 threads, 4 elems each
  int4 pl = ((const int4*)pos_list)[t];
  int sh = slot_off[16] + t;
  ushort4 a = ((const ushort4*)(y + (size_t)sh * DDIM))[c];
  ushort4 b = ((const ushort4*)(y + (size_t)pl.x * DDIM))[c];
  ushort4 d = ((const ushort4*)(y + (size_t)pl.y * DDIM))[c];
  ushort4 e = ((const ushort4*)(y + (size_t)pl.z * DDIM))[c];
  ushort4 f = ((const ushort4*)(y + (size_t)pl.w * DDIM))[c];
  float4 s;
  s.x = bf2f(a.x) + bf2f(b.x) + bf2f(d.x) + bf2f(e.x) + bf2f(f.x);
  s.y = bf2f(a.y) + bf2f(b.y) + bf2f(d.y) + bf2f(e.y) + bf2f(f.y);
  s.z = bf2f(a.z) + bf2f(b.z) + bf2f(d.z) + bf2f(e.z) + bf2f(f.z);
  s.w = bf2f(a.w) + bf2f(b.w) + bf2f(d.w) + bf2f(e.w) + bf2f(f.w);
  ((float4*)(out + (size_t)t * DDIM))[c] = s;
}

extern "C" void kernel_launch(void* const* d_in, const int* in_sizes, int n_in,
                              void* d_out, int out_size, void* d_ws, size_t ws_size,
                              hipStream_t stream) {
  const float* x      = (const float*)d_in[0];
  const float* gate_w = (const float*)d_in[1];
  const float* rbias  = (const float*)d_in[2];
  const float* w1     = (const float*)d_in[3];
  const float* w2     = (const float*)d_in[4];
  const float* w3     = (const float*)d_in[5];
  const float* sw1    = (const float*)d_in[6];
  const float* sw2    = (const float*)d_in[7];
  const float* sw3    = (const float*)d_in[8];
  float* out = (float*)d_out;

  char* ws = (char*)d_ws;
  size_t off = 0;
  auto alloc = [&](size_t bytes) -> char* {
    char* p = ws + off;
    off += (bytes + 255) & ~(size_t)255;
    return p;
  };
  u16* x_bf  = (u16*)alloc((size_t)NT * DDIM * 2);
  u16* w1t   = (u16*)alloc((size_t)NEXP * HPAD * DDIM * 2);
  u16* w2t   = (u16*)alloc((size_t)NEXP * HPAD * DDIM * 2);
  u16* w3t   = (u16*)alloc((size_t)NEXP * DDIM * HPAD * 2);
  u16* sw1t  = (u16*)alloc((size_t)HPAD * DDIM * 2);
  u16* sw2t  = (u16*)alloc((size_t)HPAD * DDIM * 2);
  u16* sw3t  = (u16*)alloc((size_t)DDIM * HPAD * 2);
  int*   counts   = (int*)alloc(64 * 4);
  int*   top_e    = (int*)alloc((size_t)NT * 4 * 4);
  float* top_w    = (float*)alloc((size_t)NT * 4 * 4);
  int*   top_pos  = (int*)alloc((size_t)NT * 4 * 4);
  int*   slot_off = (int*)alloc(32 * 4);
  int*   ntiles   = (int*)alloc(256);
  int2*  desc     = (int2*)alloc((size_t)MAXTILES * 8);
  int*   tok_pad  = (int*)alloc((size_t)MAXSLOTS * 4);
  float* w_pad    = (float*)alloc((size_t)MAXSLOTS * 4);
  int*   pos_list = (int*)alloc((size_t)NT * 4 * 4);
  size_t y_off = off;
  u16* y = (u16*)alloc((size_t)MAXSLOTS * DDIM * 2);
  size_t h_off_y = off;
  (void)in_sizes; (void)n_in; (void)ws_size;

  // ---- adaptive workspace sizing: h chunk rows + mode ----
  const size_t per_row = (size_t)HPAD * 2;
  bool ymode;
  size_t h_off, rows_avail;
  size_t avail_y = (ws_size > h_off_y) ? (ws_size - h_off_y) : 0;
  if (avail_y / per_row >= 10496) {     // y + >= 1/8 of slots fits
    ymode = true; h_off = h_off_y; rows_avail = avail_y / per_row;
  } else {                              // reclaim y space, atomic mode
    ymode = false; h_off = y_off;
    size_t avail_a = (ws_size > y_off) ? (ws_size - y_off) : 0;
    rows_avail = avail_a / per_row;
  }
  int CS;
  if (rows_avail >= (size_t)MAXSLOTS) CS = MAXSLOTS;
  else CS = (int)((rows_avail / BM) * BM);
  if (CS < BM) CS = BM;
  int NCH = (MAXSLOTS + CS - 1) / CS;
  u16* h = (u16*)(ws + h_off);

  hipMemsetAsync(counts, 0, 64 * 4, stream);
  hipMemsetAsync(tok_pad, 0, (size_t)MAXSLOTS * 4, stream);
  hipMemsetAsync(w_pad, 0, (size_t)MAXSLOTS * 4, stream);
  if (!ymode) hipMemsetAsync(out, 0, (size_t)out_size * 4, stream);

  int n8 = NT * DDIM / 8;
  convert_x_kernel<<<n8 / 256, 256, 0, stream>>>(x, x_bf, n8);

  dim3 tb(32, 8);
  transpose12_kernel<<<dim3(HPAD / 32, DDIM / 32, NEXP), tb, 0, stream>>>(w1, w1t);
  transpose12_kernel<<<dim3(HPAD / 32, DDIM / 32, NEXP), tb, 0, stream>>>(w2, w2t);
  transpose12_kernel<<<dim3(HPAD / 32, DDIM / 32, 1),    tb, 0, stream>>>(sw1, sw1t);
  transpose12_kernel<<<dim3(HPAD / 32, DDIM / 32, 1),    tb, 0, stream>>>(sw2, sw2t);
  transpose3_kernel<<<dim3(DDIM / 32, HPAD / 32, NEXP),  tb, 0, stream>>>(w3, w3t);
  transpose3_kernel<<<dim3(DDIM / 32, HPAD / 32, 1),     tb, 0, stream>>>(sw3, sw3t);

  routing_kernel<<<NT / 8, 512, 0, stream>>>(x, gate_w, rbias, top_e, top_w);
  rank_kernel<<<NT / 1024, 1024, 0, stream>>>(top_e, counts, top_pos);
  finalize_kernel<<<1, 64, 0, stream>>>(counts, slot_off, ntiles, desc);
  scatter_kernel<<<NT / 256, 256, 0, stream>>>(top_e, top_w, top_pos, slot_off,
                                               tok_pad, w_pad, pos_list);

  for (int c = 0; c < NCH; ++c) {
    int lo = c * CS;
    int ntc = (MAXSLOTS - lo < CS ? MAXSLOTS - lo : CS) >> 7;   // tiles this chunk
    gemm1_kernel<<<dim3(ntc, HPAD / 64), 256, 0, stream>>>(
        x_bf, w1t, w2t, sw1t, sw2t, ntiles, desc, tok_pad, h, lo, ntc);
    if (ymode)
      gemm2_kernel<true><<<dim3(ntc, DDIM / 128), 256, 0, stream>>>(
          h, w3t, sw3t, ntiles, desc, tok_pad, w_pad, y, out, lo, ntc);
    else
      gemm2_kernel<false><<<dim3(ntc, DDIM / 128), 256, 0, stream>>>(
          h, w3t, sw3t, ntiles, desc, tok_pad, w_pad, y, out, lo, ntc);
  }
  if (ymode) reduce_kernel<<<NT, 128, 0, stream>>>(y, pos_list, slot_off, out);
}

// Round 6
// 658.154 us; speedup vs baseline: 3.8327x; 1.0222x over previous
//
#include <hip/hip_runtime.h>

#define NT    16384
#define DDIM  512
#define HDIM  1365
#define HPAD  1408
#define NEXP  16
#define BK    64
#define BM    256
#define MAXTILES 336
#define MAXSLOTS 86016   // 336 * 256

typedef unsigned short u16;
typedef unsigned int   u32;
typedef __attribute__((ext_vector_type(8))) __bf16 bf16x8;
typedef __attribute__((ext_vector_type(4))) float  f32x4;
typedef __attribute__((address_space(3))) void lds_void;
typedef __attribute__((address_space(1))) void glb_void;

__device__ __forceinline__ u16 f2bf(float f) {
  union { float f; u32 u; } v; v.f = f;
  u32 u = v.u;
  u += 0x7fffu + ((u >> 16) & 1u);
  return (u16)(u >> 16);
}

__device__ __forceinline__ float bf2f(u16 b) {
  union { u32 u; float f; } v; v.u = ((u32)b) << 16;
  return v.f;
}

__device__ __forceinline__ f32x4 mfma16(bf16x8 a, bf16x8 b, f32x4 c) {
  return __builtin_amdgcn_mfma_f32_16x16x32_bf16(a, b, c, 0, 0, 0);
}

__device__ __forceinline__ void gload16(const u16* g, u16* l) {
  __builtin_amdgcn_global_load_lds((const glb_void*)g, (lds_void*)l, 16, 0, 0);
}

// kf-half frag read: half = [128 ldsrows][128B], tile-row r at ldsrow r>>1,
// slot = ((r&1)*4 | lk) ^ ((r>>1)&7). Exactly 2-way bank aliasing (free).
__device__ __forceinline__ bf16x8 fragk(const u16* half, int row, int lk) {
  int b = ((row >> 1) << 7) + (((((row & 1) << 2) | lk) ^ ((row >> 1) & 7)) << 4);
  return *(const bf16x8*)((const char*)half + b);
}

// m204 bijective XCD swizzle for arbitrary n (bid < n)
__device__ __forceinline__ int swz_n(int bid, int n) {
  int q = n >> 3, r = n & 7;
  int xcd = bid & 7, j = bid >> 3;
  return (xcd < r ? xcd * (q + 1) : r * (q + 1) + (xcd - r) * q) + j;
}

// ---------------- x fp32 -> bf16 ----------------
__global__ void convert_x_kernel(const float* __restrict__ in, u16* __restrict__ out, int n8) {
  int i = blockIdx.x * 256 + threadIdx.x;
  if (i >= n8) return;
  float4 a = ((const float4*)in)[2 * i];
  float4 b = ((const float4*)in)[2 * i + 1];
  u16 r[8] = {f2bf(a.x), f2bf(a.y), f2bf(a.z), f2bf(a.w),
              f2bf(b.x), f2bf(b.y), f2bf(b.z), f2bf(b.w)};
  ((uint4*)out)[i] = *(const uint4*)r;
}

// ---------- w1/w2 (E,D,H) fp32 -> (E,HPAD,D) bf16, zero-padded ----------
__global__ void transpose12_kernel(const float* __restrict__ in, u16* __restrict__ out) {
  __shared__ float tile[32][33];
  int e = blockIdx.z;
  int h0 = blockIdx.x * 32, d0 = blockIdx.y * 32;
  int tx = threadIdx.x, ty = threadIdx.y;
#pragma unroll
  for (int r = 0; r < 4; ++r) {
    int d = d0 + ty + r * 8, h = h0 + tx;
    float v = (h < HDIM) ? in[((size_t)e * DDIM + d) * HDIM + h] : 0.f;
    tile[ty + r * 8][tx] = v;
  }
  __syncthreads();
#pragma unroll
  for (int r = 0; r < 4; ++r) {
    int h = h0 + ty + r * 8, d = d0 + tx;
    out[((size_t)e * HPAD + h) * DDIM + d] = f2bf(tile[tx][ty + r * 8]);
  }
}

// ---------- w3 (E,H,D) fp32 -> (E,D,HPAD) bf16, zero-padded ----------
__global__ void transpose3_kernel(const float* __restrict__ in, u16* __restrict__ out) {
  __shared__ float tile[32][33];
  int e = blockIdx.z;
  int d0 = blockIdx.x * 32, h0 = blockIdx.y * 32;
  int tx = threadIdx.x, ty = threadIdx.y;
#pragma unroll
  for (int r = 0; r < 4; ++r) {
    int h = h0 + ty + r * 8, d = d0 + tx;
    float v = (h < HDIM) ? in[((size_t)e * HDIM + h) * DDIM + d] : 0.f;
    tile[ty + r * 8][tx] = v;
  }
  __syncthreads();
#pragma unroll
  for (int r = 0; r < 4; ++r) {
    int d = d0 + ty + r * 8, h = h0 + tx;
    out[((size_t)e * DDIM + d) * HPAD + h] = f2bf(tile[tx][ty + r * 8]);
  }
}

// ---------------- R1: logits, top-4, softmax (8 waves/block, gw in LDS) ----------------
__global__ __launch_bounds__(512) void routing_kernel(
    const float* __restrict__ x, const float* __restrict__ gw,
    const float* __restrict__ rbias,
    int* __restrict__ top_e, float* __restrict__ top_w) {
  __shared__ float gwT[NEXP * DDIM];
  int tid = threadIdx.x;
  for (int i = tid; i < NEXP * DDIM; i += 512) {
    int d = i >> 4, e = i & 15;
    gwT[e * DDIM + d] = gw[i];
  }
  __syncthreads();
  int w = tid >> 6, lane = tid & 63;
  int t = blockIdx.x * 8 + w;
  const float* xr = x + (size_t)t * DDIM;
  float xv[8];
#pragma unroll
  for (int k = 0; k < 8; ++k) xv[k] = xr[lane + (k << 6)];
  float acc[NEXP];
#pragma unroll
  for (int e = 0; e < NEXP; ++e) {
    const float* ge = gwT + e * DDIM + lane;
    float s = 0.f;
#pragma unroll
    for (int k = 0; k < 8; ++k) s += xv[k] * ge[k << 6];
#pragma unroll
    for (int off = 32; off; off >>= 1) s += __shfl_xor(s, off);
    acc[e] = s + rbias[e];
  }
  if (lane == 0) {
    int sel[4]; float sv[4];
    unsigned used = 0;
#pragma unroll
    for (int i = 0; i < 4; ++i) {
      float best = -1e30f; int bi = 0;
#pragma unroll
      for (int e = 0; e < NEXP; ++e) {
        bool ok = !((used >> e) & 1u) && acc[e] > best;
        best = ok ? acc[e] : best;
        bi   = ok ? e : bi;
      }
      used |= 1u << bi; sel[i] = bi; sv[i] = best;
    }
    float m = sv[0];
    float ex[4]; float s = 0.f;
#pragma unroll
    for (int i = 0; i < 4; ++i) { ex[i] = __expf(sv[i] - m); s += ex[i]; }
    float inv = 1.f / s;
#pragma unroll
    for (int i = 0; i < 4; ++i) {
      top_e[t * 4 + i] = sel[i];
      top_w[t * 4 + i] = ex[i] * inv;
    }
  }
}

// ---------------- R2: hierarchical counting + rank ----------------
__global__ __launch_bounds__(1024) void rank_kernel(const int* __restrict__ top_e,
                                                    int* __restrict__ counts,
                                                    int* __restrict__ top_pos) {
  __shared__ int hist[NEXP], base[NEXP];
  int tid = threadIdx.x;
  int t = blockIdx.x * 1024 + tid;
  if (tid < NEXP) hist[tid] = 0;
  __syncthreads();
  int e4[4], r4[4];
#pragma unroll
  for (int i = 0; i < 4; ++i) {
    e4[i] = top_e[t * 4 + i];
    r4[i] = atomicAdd(&hist[e4[i]], 1);
  }
  __syncthreads();
  if (tid < NEXP) base[tid] = atomicAdd(&counts[tid], hist[tid]);
  __syncthreads();
#pragma unroll
  for (int i = 0; i < 4; ++i) top_pos[t * 4 + i] = base[e4[i]] + r4[i];
}

// ---------------- finalize: padded slot offsets + tile descriptors ----------------
__global__ void finalize_kernel(const int* __restrict__ counts, int* __restrict__ slot_off,
                                int* __restrict__ ntiles, int2* __restrict__ desc) {
  if (threadIdx.x != 0) return;
  int off = 0, td = 0;
  for (int e = 0; e < 17; ++e) {
    int c = (e == 16) ? NT : counts[e];
    slot_off[e] = off;
    int nt = (c + BM - 1) / BM;
    for (int i = 0; i < nt; ++i) { desc[td] = make_int2(e, off + i * BM); ++td; }
    off += nt * BM;
  }
  slot_off[17] = off;
  *ntiles = td;
}

// ---------------- scatter ----------------
__global__ void scatter_kernel(const int* __restrict__ top_e, const float* __restrict__ top_w,
                               const int* __restrict__ top_pos, const int* __restrict__ slot_off,
                               int* __restrict__ tok_pad, float* __restrict__ w_pad,
                               int* __restrict__ pos_list) {
  int t = blockIdx.x * 256 + threadIdx.x;
  if (t >= NT) return;
#pragma unroll
  for (int i = 0; i < 4; ++i) {
    int e = top_e[t * 4 + i];
    int slot = slot_off[e] + top_pos[t * 4 + i];
    tok_pad[slot] = t;
    w_pad[slot] = top_w[t * 4 + i];
    pos_list[t * 4 + i] = slot;
  }
  int sh = slot_off[16] + t;
  tok_pad[sh] = t;
  w_pad[sh] = 1.f;
}

// ============ K1: grouped GEMM1 + SwiGLU, 256x256 tile, counted-vmcnt 4-phase ============
// 512 threads = 8 waves (2M x 4N). B rows 0..255: 16-row groups alternate W1/W2.
// LDS: A,B each 2buf x 2kf-halves x [256 rows x 32 k] (paired-row swizzled layout).
__global__ __launch_bounds__(512, 2) void gemm1_kernel(
    const u16* __restrict__ x_bf, const u16* __restrict__ w1t, const u16* __restrict__ w2t,
    const u16* __restrict__ sw1t, const u16* __restrict__ sw2t,
    const int* __restrict__ ntiles, const int2* __restrict__ desc,
    const int* __restrict__ tok_pad, u16* __restrict__ h, int lo, int ntc) {
  int ti = (lo >> 8) + swz_n(blockIdx.x, ntc);
  if (ti >= *ntiles) return;
  int2 de = desc[ti];
  int e = de.x, m0 = de.y;
  int n0h = blockIdx.y * 128;
  const u16* W1 = (e == 16) ? sw1t : (w1t + (size_t)e * HPAD * DDIM);
  const u16* W2 = (e == 16) ? sw2t : (w2t + (size_t)e * HPAD * DDIM);

  __shared__ u16 As[32768];   // 64 KiB
  __shared__ u16 Bs[32768];   // 64 KiB

  int tid = threadIdx.x, w = tid >> 6, lane = tid & 63;
  int wm = w >> 2, wn = w & 3, lr = lane & 15, lk = lane >> 4;

  // staging: per thread 2 loads/half; idx = l*512+tid -> ldsrow=idx>>3, slot=idx&7
  int ldsrow0 = tid >> 3, slot = tid & 7;
  int sx = slot ^ (ldsrow0 & 7);                 // (ldsrow&7) same for l=0,1
  int r0 = ldsrow0 * 2 + (sx >> 2);              // tile row, l=0; l=1 adds 128
  int sch = (sx & 3) << 3;                       // source k-elem offset within kf-half
  const u16* a0 = x_bf + (size_t)tok_pad[m0 + r0] * DDIM + sch;
  const u16* a1 = x_bf + (size_t)tok_pad[m0 + 128 + r0] * DDIM + sch;
  auto browp = [&](int r) {
    int grp = r >> 4;
    const u16* Wsrc = (grp & 1) ? W2 : W1;
    int hrow = n0h + ((grp >> 1) << 4) + (r & 15);
    return Wsrc + (size_t)hrow * DDIM + sch;
  };
  const u16* b0 = browp(r0);
  const u16* b1 = browp(128 + r0);
  int sdst = w << 9;                             // wave-uniform dest (u16)

  auto stageA = [&](int kc, int kf, int buf) {
    u16* d = As + buf * 16384 + kf * 8192 + sdst;
    gload16(a0 + kc + kf * 32, d);
    gload16(a1 + kc + kf * 32, d + 4096);
  };
  auto stageB = [&](int kc, int kf, int buf) {
    u16* d = Bs + buf * 16384 + kf * 8192 + sdst;
    gload16(b0 + kc + kf * 32, d);
    gload16(b1 + kc + kf * 32, d + 4096);
  };

  f32x4 acc[8][4] = {};

  // prologue: stage tile 0 fully (A0,B0,A1,B1)
  stageA(0, 0, 0); stageB(0, 0, 0); stageA(0, 1, 0); stageB(0, 1, 0);

  const int NTK = DDIM / BK;   // 8
  for (int t = 0; t < NTK; ++t) {
    int cur = t & 1, nxt = cur ^ 1;
    int tn = (t + 1 < NTK) ? t + 1 : t;          // clamped tail keeps vmcnt uniform
    int kc = tn * BK;
    const u16* A0 = As + cur * 16384;
    const u16* A1 = A0 + 8192;
    const u16* B0 = Bs + cur * 16384;
    const u16* B1 = B0 + 8192;
    bf16x8 afr[4], bfr[4];
    // ---- phase 0: needs kf0 halves of tile t (staged 4&3 phases ago)
    asm volatile("s_waitcnt vmcnt(4)" ::: "memory");
    __builtin_amdgcn_s_barrier();
    __builtin_amdgcn_sched_barrier(0);
    stageA(kc, 0, nxt);
#pragma unroll
    for (int nf = 0; nf < 4; ++nf) bfr[nf] = fragk(B0, wn * 64 + nf * 16 + lr, lk);
#pragma unroll
    for (int mf = 0; mf < 4; ++mf) afr[mf] = fragk(A0, wm * 128 + mf * 16 + lr, lk);
    __builtin_amdgcn_s_setprio(1);
#pragma unroll
    for (int mf = 0; mf < 4; ++mf)
#pragma unroll
      for (int nf = 0; nf < 4; ++nf)
        acc[mf][nf] = mfma16(afr[mf], bfr[nf], acc[mf][nf]);
    __builtin_amdgcn_s_setprio(0);
    // ---- phase 1: same kf0, A rows mf4-7 (B frags reused)
    stageB(kc, 0, nxt);
#pragma unroll
    for (int mf = 0; mf < 4; ++mf) afr[mf] = fragk(A0, wm * 128 + (mf + 4) * 16 + lr, lk);
    __builtin_amdgcn_s_setprio(1);
#pragma unroll
    for (int mf = 0; mf < 4; ++mf)
#pragma unroll
      for (int nf = 0; nf < 4; ++nf)
        acc[mf + 4][nf] = mfma16(afr[mf], bfr[nf], acc[mf + 4][nf]);
    __builtin_amdgcn_s_setprio(0);
    // ---- phase 2: needs kf1 halves of tile t
    asm volatile("s_waitcnt vmcnt(4)" ::: "memory");
    __builtin_amdgcn_s_barrier();
    __builtin_amdgcn_sched_barrier(0);
    stageA(kc, 1, nxt);
#pragma unroll
    for (int nf = 0; nf < 4; ++nf) bfr[nf] = fragk(B1, wn * 64 + nf * 16 + lr, lk);
#pragma unroll
    for (int mf = 0; mf < 4; ++mf) afr[mf] = fragk(A1, wm * 128 + mf * 16 + lr, lk);
    __builtin_amdgcn_s_setprio(1);
#pragma unroll
    for (int mf = 0; mf < 4; ++mf)
#pragma unroll
      for (int nf = 0; nf < 4; ++nf)
        acc[mf][nf] = mfma16(afr[mf], bfr[nf], acc[mf][nf]);
    __builtin_amdgcn_s_setprio(0);
    // ---- phase 3
    stageB(kc, 1, nxt);
#pragma unroll
    for (int mf = 0; mf < 4; ++mf) afr[mf] = fragk(A1, wm * 128 + (mf + 4) * 16 + lr, lk);
    __builtin_amdgcn_s_setprio(1);
#pragma unroll
    for (int mf = 0; mf < 4; ++mf)
#pragma unroll
      for (int nf = 0; nf < 4; ++nf)
        acc[mf + 4][nf] = mfma16(afr[mf], bfr[nf], acc[mf + 4][nf]);
    __builtin_amdgcn_s_setprio(0);
  }

  // epilogue: nf even = g (W1), nf odd = u (W2), same h-col -> register-local SwiGLU
#pragma unroll
  for (int mf = 0; mf < 8; ++mf)
#pragma unroll
    for (int hc = 0; hc < 2; ++hc)
#pragma unroll
      for (int j = 0; j < 4; ++j) {
        float g = acc[mf][hc * 2][j], u = acc[mf][hc * 2 + 1][j];
        float hv = g * u / (1.f + __expf(-g));
        int row = wm * 128 + mf * 16 + lk * 4 + j;
        int hcol = n0h + (wn * 2 + hc) * 16 + lr;
        h[(size_t)(m0 - lo + row) * HPAD + hcol] = f2bf(hv);
      }
}

// ============ K2: grouped GEMM2, weighted, 256x256 tile, same schedule ============
template <bool YMODE>
__global__ __launch_bounds__(512, 2) void gemm2_kernel(
    const u16* __restrict__ h, const u16* __restrict__ w3t, const u16* __restrict__ sw3t,
    const int* __restrict__ ntiles, const int2* __restrict__ desc,
    const int* __restrict__ tok_pad, const float* __restrict__ w_pad,
    u16* __restrict__ y, float* __restrict__ out, int lo, int ntc) {
  int ti = (lo >> 8) + swz_n(blockIdx.x, ntc);
  if (ti >= *ntiles) return;
  int2 de = desc[ti];
  int e = de.x, m0 = de.y;
  int n0 = blockIdx.y * 256;
  const u16* W3 = (e == 16) ? sw3t : (w3t + (size_t)e * DDIM * HPAD);

  __shared__ u16 As[32768];
  __shared__ u16 Bs[32768];
  __shared__ float swl[BM];

  int tid = threadIdx.x, w = tid >> 6, lane = tid & 63;
  int wm = w >> 2, wn = w & 3, lr = lane & 15, lk = lane >> 4;

  if (tid < BM) swl[tid] = w_pad[m0 + tid];

  int ldsrow0 = tid >> 3, slot = tid & 7;
  int sx = slot ^ (ldsrow0 & 7);
  int r0 = ldsrow0 * 2 + (sx >> 2);
  int sch = (sx & 3) << 3;
  const u16* a0 = h + (size_t)(m0 - lo + r0) * HPAD + sch;
  const u16* a1 = a0 + (size_t)128 * HPAD;
  const u16* b0 = W3 + (size_t)(n0 + r0) * HPAD + sch;
  const u16* b1 = b0 + (size_t)128 * HPAD;
  int sdst = w << 9;

  auto stageA = [&](int kc, int kf, int buf) {
    u16* d = As + buf * 16384 + kf * 8192 + sdst;
    gload16(a0 + kc + kf * 32, d);
    gload16(a1 + kc + kf * 32, d + 4096);
  };
  auto stageB = [&](int kc, int kf, int buf) {
    u16* d = Bs + buf * 16384 + kf * 8192 + sdst;
    gload16(b0 + kc + kf * 32, d);
    gload16(b1 + kc + kf * 32, d + 4096);
  };

  f32x4 acc[8][4] = {};

  stageA(0, 0, 0); stageB(0, 0, 0); stageA(0, 1, 0); stageB(0, 1, 0);

  const int NTK = HPAD / BK;   // 22
  for (int t = 0; t < NTK; ++t) {
    int cur = t & 1, nxt = cur ^ 1;
    int tn = (t + 1 < NTK) ? t + 1 : t;
    int kc = tn * BK;
    const u16* A0 = As + cur * 16384;
    const u16* A1 = A0 + 8192;
    const u16* B0 = Bs + cur * 16384;
    const u16* B1 = B0 + 8192;
    bf16x8 afr[4], bfr[4];
    // ---- phase 0
    asm volatile("s_waitcnt vmcnt(4)" ::: "memory");
    __builtin_amdgcn_s_barrier();
    __builtin_amdgcn_sched_barrier(0);
    stageA(kc, 0, nxt);
#pragma unroll
    for (int nf = 0; nf < 4; ++nf) bfr[nf] = fragk(B0, wn * 64 + nf * 16 + lr, lk);
#pragma unroll
    for (int mf = 0; mf < 4; ++mf) afr[mf] = fragk(A0, wm * 128 + mf * 16 + lr, lk);
    __builtin_amdgcn_s_setprio(1);
#pragma unroll
    for (int mf = 0; mf < 4; ++mf)
#pragma unroll
      for (int nf = 0; nf < 4; ++nf)
        acc[mf][nf] = mfma16(afr[mf], bfr[nf], acc[mf][nf]);
    __builtin_amdgcn_s_setprio(0);
    // ---- phase 1
    stageB(kc, 0, nxt);
#pragma unroll
    for (int mf = 0; mf < 4; ++mf) afr[mf] = fragk(A0, wm * 128 + (mf + 4) * 16 + lr, lk);
    __builtin_amdgcn_s_setprio(1);
#pragma unroll
    for (int mf = 0; mf < 4; ++mf)
#pragma unroll
      for (int nf = 0; nf < 4; ++nf)
        acc[mf + 4][nf] = mfma16(afr[mf], bfr[nf], acc[mf + 4][nf]);
    __builtin_amdgcn_s_setprio(0);
    // ---- phase 2
    asm volatile("s_waitcnt vmcnt(4)" ::: "memory");
    __builtin_amdgcn_s_barrier();
    __builtin_amdgcn_sched_barrier(0);
    stageA(kc, 1, nxt);
#pragma unroll
    for (int nf = 0; nf < 4; ++nf) bfr[nf] = fragk(B1, wn * 64 + nf * 16 + lr, lk);
#pragma unroll
    for (int mf = 0; mf < 4; ++mf) afr[mf] = fragk(A1, wm * 128 + mf * 16 + lr, lk);
    __builtin_amdgcn_s_setprio(1);
#pragma unroll
    for (int mf = 0; mf < 4; ++mf)
#pragma unroll
      for (int nf = 0; nf < 4; ++nf)
        acc[mf][nf] = mfma16(afr[mf], bfr[nf], acc[mf][nf]);
    __builtin_amdgcn_s_setprio(0);
    // ---- phase 3
    stageB(kc, 1, nxt);
#pragma unroll
    for (int mf = 0; mf < 4; ++mf) afr[mf] = fragk(A1, wm * 128 + (mf + 4) * 16 + lr, lk);
    __builtin_amdgcn_s_setprio(1);
#pragma unroll
    for (int mf = 0; mf < 4; ++mf)
#pragma unroll
      for (int nf = 0; nf < 4; ++nf)
        acc[mf + 4][nf] = mfma16(afr[mf], bfr[nf], acc[mf + 4][nf]);
    __builtin_amdgcn_s_setprio(0);
  }

#pragma unroll
  for (int mf = 0; mf < 8; ++mf)
#pragma unroll
    for (int j = 0; j < 4; ++j) {
      int row = wm * 128 + mf * 16 + lk * 4 + j;
      float wv = swl[row];
      if constexpr (YMODE) {
        u16* yrow = y + (size_t)(m0 + row) * DDIM + n0;
#pragma unroll
        for (int nf = 0; nf < 4; ++nf)
          yrow[wn * 64 + nf * 16 + lr] = f2bf(acc[mf][nf][j] * wv);
      } else {
        float* orow = out + (size_t)tok_pad[m0 + row] * DDIM + n0;
#pragma unroll
        for (int nf = 0; nf < 4; ++nf)
          atomicAdd(&orow[wn * 64 + nf * 16 + lr], acc[mf][nf][j] * wv);
      }
    }
}

// ---------------- reduce: out[t] = y_shared + sum of 4 routed y ----------------
__global__ void reduce_kernel(const u16* __restrict__ y, const int* __restrict__ pos_list,
                              const int* __restrict__ slot_off, float* __restrict__ out) {
  int t = blockIdx.x;
  int c = threadIdx.x;
  int4 pl = ((const int4*)pos_list)[t];
  int sh = slot_off[16] + t;
  ushort4 a = ((const ushort4*)(y + (size_t)sh * DDIM))[c];
  ushort4 b = ((const ushort4*)(y + (size_t)pl.x * DDIM))[c];
  ushort4 d = ((const ushort4*)(y + (size_t)pl.y * DDIM))[c];
  ushort4 e = ((const ushort4*)(y + (size_t)pl.z * DDIM))[c];
  ushort4 f = ((const ushort4*)(y + (size_t)pl.w * DDIM))[c];
  float4 s;
  s.x = bf2f(a.x) + bf2f(b.x) + bf2f(d.x) + bf2f(e.x) + bf2f(f.x);
  s.y = bf2f(a.y) + bf2f(b.y) + bf2f(d.y) + bf2f(e.y) + bf2f(f.y);
  s.z = bf2f(a.z) + bf2f(b.z) + bf2f(d.z) + bf2f(e.z) + bf2f(f.z);
  s.w = bf2f(a.w) + bf2f(b.w) + bf2f(d.w) + bf2f(e.w) + bf2f(f.w);
  ((float4*)(out + (size_t)t * DDIM))[c] = s;
}

extern "C" void kernel_launch(void* const* d_in, const int* in_sizes, int n_in,
                              void* d_out, int out_size, void* d_ws, size_t ws_size,
                              hipStream_t stream) {
  const float* x      = (const float*)d_in[0];
  const float* gate_w = (const float*)d_in[1];
  const float* rbias  = (const float*)d_in[2];
  const float* w1     = (const float*)d_in[3];
  const float* w2     = (const float*)d_in[4];
  const float* w3     = (const float*)d_in[5];
  const float* sw1    = (const float*)d_in[6];
  const float* sw2    = (const float*)d_in[7];
  const float* sw3    = (const float*)d_in[8];
  float* out = (float*)d_out;

  char* ws = (char*)d_ws;
  size_t off = 0;
  auto alloc = [&](size_t bytes) -> char* {
    char* p = ws + off;
    off += (bytes + 255) & ~(size_t)255;
    return p;
  };
  u16* x_bf  = (u16*)alloc((size_t)NT * DDIM * 2);
  u16* w1t   = (u16*)alloc((size_t)NEXP * HPAD * DDIM * 2);
  u16* w2t   = (u16*)alloc((size_t)NEXP * HPAD * DDIM * 2);
  u16* w3t   = (u16*)alloc((size_t)NEXP * DDIM * HPAD * 2);
  u16* sw1t  = (u16*)alloc((size_t)HPAD * DDIM * 2);
  u16* sw2t  = (u16*)alloc((size_t)HPAD * DDIM * 2);
  u16* sw3t  = (u16*)alloc((size_t)DDIM * HPAD * 2);
  int*   counts   = (int*)alloc(64 * 4);
  int*   top_e    = (int*)alloc((size_t)NT * 4 * 4);
  float* top_w    = (float*)alloc((size_t)NT * 4 * 4);
  int*   top_pos  = (int*)alloc((size_t)NT * 4 * 4);
  int*   slot_off = (int*)alloc(32 * 4);
  int*   ntiles   = (int*)alloc(256);
  int2*  desc     = (int2*)alloc((size_t)MAXTILES * 8);
  int*   tok_pad  = (int*)alloc((size_t)MAXSLOTS * 4);
  float* w_pad    = (float*)alloc((size_t)MAXSLOTS * 4);
  int*   pos_list = (int*)alloc((size_t)NT * 4 * 4);
  size_t y_off = off;
  u16* y = (u16*)alloc((size_t)MAXSLOTS * DDIM * 2);
  size_t h_off_y = off;
  (void)in_sizes; (void)n_in; (void)ws_size;

  // ---- adaptive workspace sizing ----
  const size_t per_row = (size_t)HPAD * 2;
  bool ymode;
  size_t h_off, rows_avail;
  size_t avail_y = (ws_size > h_off_y) ? (ws_size - h_off_y) : 0;
  if (avail_y / per_row >= 10752) {
    ymode = true; h_off = h_off_y; rows_avail = avail_y / per_row;
  } else {
    ymode = false; h_off = y_off;
    size_t avail_a = (ws_size > y_off) ? (ws_size - y_off) : 0;
    rows_avail = avail_a / per_row;
  }
  int CS;
  if (rows_avail >= (size_t)MAXSLOTS) CS = MAXSLOTS;
  else CS = (int)((rows_avail / BM) * BM);
  if (CS < BM) CS = BM;
  int NCH = (MAXSLOTS + CS - 1) / CS;
  u16* h = (u16*)(ws + h_off);

  hipMemsetAsync(counts, 0, 64 * 4, stream);
  hipMemsetAsync(tok_pad, 0, (size_t)MAXSLOTS * 4, stream);
  hipMemsetAsync(w_pad, 0, (size_t)MAXSLOTS * 4, stream);
  if (!ymode) hipMemsetAsync(out, 0, (size_t)out_size * 4, stream);

  int n8 = NT * DDIM / 8;
  convert_x_kernel<<<n8 / 256, 256, 0, stream>>>(x, x_bf, n8);

  dim3 tb(32, 8);
  transpose12_kernel<<<dim3(HPAD / 32, DDIM / 32, NEXP), tb, 0, stream>>>(w1, w1t);
  transpose12_kernel<<<dim3(HPAD / 32, DDIM / 32, NEXP), tb, 0, stream>>>(w2, w2t);
  transpose12_kernel<<<dim3(HPAD / 32, DDIM / 32, 1),    tb, 0, stream>>>(sw1, sw1t);
  transpose12_kernel<<<dim3(HPAD / 32, DDIM / 32, 1),    tb, 0, stream>>>(sw2, sw2t);
  transpose3_kernel<<<dim3(DDIM / 32, HPAD / 32, NEXP),  tb, 0, stream>>>(w3, w3t);
  transpose3_kernel<<<dim3(DDIM / 32, HPAD / 32, 1),     tb, 0, stream>>>(sw3, sw3t);

  routing_kernel<<<NT / 8, 512, 0, stream>>>(x, gate_w, rbias, top_e, top_w);
  rank_kernel<<<NT / 1024, 1024, 0, stream>>>(top_e, counts, top_pos);
  finalize_kernel<<<1, 64, 0, stream>>>(counts, slot_off, ntiles, desc);
  scatter_kernel<<<NT / 256, 256, 0, stream>>>(top_e, top_w, top_pos, slot_off,
                                               tok_pad, w_pad, pos_list);

  for (int c = 0; c < NCH; ++c) {
    int lo = c * CS;
    int ntc = (MAXSLOTS - lo < CS ? MAXSLOTS - lo : CS) >> 8;
    gemm1_kernel<<<dim3(ntc, HPAD / 128), 512, 0, stream>>>(
        x_bf, w1t, w2t, sw1t, sw2t, ntiles, desc, tok_pad, h, lo, ntc);
    if (ymode)
      gemm2_kernel<true><<<dim3(ntc, DDIM / 256), 512, 0, stream>>>(
          h, w3t, sw3t, ntiles, desc, tok_pad, w_pad, y, out, lo, ntc);
    else
      gemm2_kernel<false><<<dim3(ntc, DDIM / 256), 512, 0, stream>>>(
          h, w3t, sw3t, ntiles, desc, tok_pad, w_pad, y, out, lo, ntc);
  }
  if (ymode) reduce_kernel<<<NT, 128, 0, stream>>>(y, pos_list, slot_off, out);
}